// Round 14
// baseline (923.585 us; speedup 1.0000x reference)
//
#include <hip/hip_runtime.h>
#include <cstdint>

#define ESZ 1024
#define NH 16
#define HD 64
#define NLAYER 4
#define FFD 4096
#define NB 2
#define NXTOK 1023
#define SEQ 1024
#define LNEPS 1e-5f

typedef __attribute__((ext_vector_type(8))) _Float16 f16x8;
typedef __attribute__((ext_vector_type(4))) _Float16 f16x4;
typedef __attribute__((ext_vector_type(4))) float f32x4;

__device__ __forceinline__ void gld16(const void* g, void* l) {
  __builtin_amdgcn_global_load_lds(
      (const __attribute__((address_space(1))) unsigned int*)g,
      (__attribute__((address_space(3))) unsigned int*)l, 16, 0, 0);
}

// Bijective XCD-aware block swizzle (each XCD gets a contiguous work chunk).
__device__ __forceinline__ uint3 xcd_swz() {
  unsigned gx = gridDim.x, gy = gridDim.y;
  unsigned nwg = gx * gy * gridDim.z;
  unsigned lin = (blockIdx.z * gy + blockIdx.y) * gx + blockIdx.x;
  unsigned q = nwg >> 3, r = nwg & 7;
  unsigned xcd = lin & 7, idx = lin >> 3;
  unsigned wid = (xcd < r ? xcd * (q + 1) : r * (q + 1) + (xcd - r) * q) + idx;
  uint3 o;
  o.x = wid % gx;
  unsigned t = wid / gx;
  o.y = t % gy;
  o.z = t / gy;
  return o;
}

// ---------------------------------------------------------------------------
// Shared GEMM epilogue (non-V blocks). EPI: 0 f32, 1 f16, 2 QKV head scatter.
// ---------------------------------------------------------------------------
template<int MI, int NJ, int EPI, bool RELU, int SPLITK>
__device__ __forceinline__ void gemm_epi(
    f32x4 (&acc)[MI][NJ], int m0, int n0, int wr, int wc, int lr, int hi,
    int z, size_t coff, int ldc,
    const float* bias0, const float* bias1, const float* bias2, int bstr,
    void* C0, void* C1, long sC1, long sC2, int vseg)
{
  const int rb = hi * 4;
#pragma unroll
  for (int j = 0; j < NJ; j++) {
    const int n = n0 + wc + j * 16 + lr;
    float bv = 0.f;
    if (EPI == 2) {
      int seg = n >> 10;
      const float* bp = (seg == 0) ? bias0 : ((seg == 1) ? bias1 : bias2);
      bv = bp[bstr * z + (n & 1023)];
    } else if (bias0) bv = bias0[bstr * z + n];
    if (SPLITK > 1 && z > 0) bv = 0.f;
#pragma unroll
    for (int i = 0; i < MI; i++) {
#pragma unroll
      for (int r = 0; r < 4; r++) {
        int row = m0 + wr + i * 16 + rb + r;
        float out = acc[i][j][r] + bv;
        if (RELU) out = fmaxf(out, 0.f);
        if (EPI == 0) {
          ((float*)C0)[coff + (size_t)row * ldc + n] = out;
        } else if (EPI == 1) {
          ((_Float16*)C0)[coff + (size_t)row * ldc + n] = (_Float16)out;
        } else {
          int seg = n >> 10, n1 = n & 1023, h = n1 >> 6, d = n1 & 63;
          int b = row >> 10, s = row & 1023;
          if (seg == vseg)
            ((_Float16*)C1)[(size_t)z * sC2 + (((size_t)b * NH + h) * HD + d) * SEQ + s] = (_Float16)out;
          else
            ((_Float16*)C0)[(size_t)z * sC1 + (size_t)seg * ((size_t)NB * NH * SEQ * HD)
                            + (((size_t)b * NH + h) * SEQ + s) * HD + d] = (_Float16)out;
        }
      }
    }
  }
}

// ---------------------------------------------------------------------------
// 4-wave NT MFMA GEMM, BM=BN=128, BK=64, SINGLE-buffered 32 KB LDS (m97
// structure). 8-row XOR swizzle -> ~0 bank conflicts. gld16 staging.
// EPI==2 V-blocks: LDS-transpose epilogue -> coalesced f16x8 V^T stores.
// ---------------------------------------------------------------------------
template<int BM, int BN, int EPI, bool RELU, int SPLITK>
__global__ __launch_bounds__(256)
void gemm_k(const _Float16* __restrict__ A, const _Float16* __restrict__ Bm,
            const float* __restrict__ bias0, const float* __restrict__ bias1,
            const float* __restrict__ bias2,
            void* __restrict__ C0, void* __restrict__ C1,
            int K, int lda, int ldb, int ldc,
            long sAz, long sBz, int cdiv, long sC1, long sC2, int vseg, int bstr)
{
  constexpr int MI = BM / 32, NJ = BN / 32;
  constexpr int SBUF = (BM + BN) * 64;
  constexpr int TBUF = (EPI == 2) ? 128 * 136 : 0;
  constexpr int LDSN = (TBUF > SBUF) ? TBUF : SBUF;
  __shared__ _Float16 lds[LDSN];

  const uint3 bi = xcd_swz();
  const int m0 = bi.x * BM;
  const int n0 = bi.y * BN;
  const int z = bi.z;
  const _Float16* Ab;
  const _Float16* Bb;
  size_t coff;
  if (SPLITK > 1) {
    int koff = z * (K / SPLITK);
    Ab = A + koff;
    Bb = Bm + koff;
    coff = (size_t)z * sC1;
  } else {
    Ab = A + (size_t)z * sAz;
    Bb = Bm + (size_t)z * sBz;
    coff = (size_t)(z / cdiv) * sC1 + (size_t)(z % cdiv) * sC2;
  }
  const int tid = threadIdx.x;
  const int lane = tid & 63;
  const int w = tid >> 6;
  const int lr = lane & 15;
  const int hi = lane >> 4;
  const int wr = (w >> 1) * (BM / 2);
  const int wc = (w & 1) * (BN / 2);

  const f32x4 vz = {0.f, 0.f, 0.f, 0.f};
  f32x4 acc[MI][NJ];
#pragma unroll
  for (int i = 0; i < MI; i++)
#pragma unroll
    for (int j = 0; j < NJ; j++) acc[i][j] = vz;

  const int nk = (K / SPLITK) >> 6;
  _Float16* Ah = lds;
  _Float16* Bh = lds + BM * 64;

  for (int kt = 0; kt < nk; ++kt) {
    const int k0 = kt << 6;
    __syncthreads();
#pragma unroll
    for (int c = 0; c < MI; c++) {
      int r = w * (BM / 4) + c * 8 + (lane >> 3);
      int cg = ((lane & 7) ^ (r & 7)) << 3;
      gld16(Ab + (size_t)(m0 + r) * lda + k0 + cg, Ah + (w * (BM / 4) + c * 8) * 64);
    }
#pragma unroll
    for (int c = 0; c < NJ; c++) {
      int r = w * (BN / 4) + c * 8 + (lane >> 3);
      int cg = ((lane & 7) ^ (r & 7)) << 3;
      gld16(Bb + (size_t)(n0 + r) * ldb + k0 + cg, Bh + (w * (BN / 4) + c * 8) * 64);
    }
    __syncthreads();
#pragma unroll
    for (int kk = 0; kk < 2; kk++) {
      f16x8 af[MI], bf[NJ];
#pragma unroll
      for (int i = 0; i < MI; i++) {
        int row = wr + i * 16 + lr;
        int off = ((kk << 6) | (hi << 4)) ^ ((row & 7) << 4);
        af[i] = *(const f16x8*)((const char*)Ah + row * 128 + off);
      }
#pragma unroll
      for (int j = 0; j < NJ; j++) {
        int row = wc + j * 16 + lr;
        int off = ((kk << 6) | (hi << 4)) ^ ((row & 7) << 4);
        bf[j] = *(const f16x8*)((const char*)Bh + row * 128 + off);
      }
#pragma unroll
      for (int i = 0; i < MI; i++)
#pragma unroll
        for (int j = 0; j < NJ; j++)
          acc[i][j] = __builtin_amdgcn_mfma_f32_16x16x32_f16(af[i], bf[j], acc[i][j], 0, 0, 0);
    }
  }

  if (EPI == 2 && (n0 >> 10) == vseg) {
    __syncthreads();
    _Float16* T = lds;   // [128][136]
    const float* bp = (vseg == 0) ? bias0 : ((vseg == 1) ? bias1 : bias2);
#pragma unroll
    for (int j = 0; j < NJ; j++) {
      int nloc = wc + j * 16 + lr;
      float bv = bp[bstr * z + ((n0 + nloc) & 1023)];
#pragma unroll
      for (int i = 0; i < MI; i++) {
        f16x4 tv;
#pragma unroll
        for (int r = 0; r < 4; r++) tv[r] = (_Float16)(acc[i][j][r] + bv);
        *(f16x4*)(T + nloc * 136 + wr + i * 16 + hi * 4) = tv;
      }
    }
    __syncthreads();
    int rowT = tid >> 1;
    int c0 = (tid & 1) << 6;
    int nn = (n0 & 1023) + rowT;
    int h = nn >> 6, d = nn & 63;
    int bb = m0 >> 10;
    int s0 = (m0 & 1023) + c0;
    _Float16* dst = (_Float16*)C1 + (size_t)z * sC2
                  + (((size_t)bb * NH + h) * HD + d) * SEQ + s0;
    const _Float16* src = T + rowT * 136 + c0;
#pragma unroll
    for (int t2 = 0; t2 < 8; t2++)
      *(f16x8*)(dst + t2 * 8) = *(const f16x8*)(src + t2 * 8);
    return;
  }

  gemm_epi<MI, NJ, EPI, RELU, SPLITK>(acc, m0, n0, wr, wc, lr, hi, z, coff, ldc,
                                      bias0, bias1, bias2, bstr, C0, C1, sC1, sC2, vseg);
}

// ---------------------------------------------------------------------------
// Flash attention: one block = 128 q rows of one (b,h); 4 waves x 32 q rows.
// blockIdx.z = layer. Swapped QK^T; S^T C-layout IS the B-fragment of
// mfma_16x16x16_f16 so PV needs no P relayout. setprio around MFMA clusters.
// ---------------------------------------------------------------------------
template<bool CAUSAL>
__global__ __launch_bounds__(256)
void flash_k(const _Float16* __restrict__ qh, const _Float16* __restrict__ kh,
             const _Float16* __restrict__ vTp, _Float16* __restrict__ ob,
             long qs, long ks, long vs, long os)
{
  __shared__ _Float16 Kl[2][64 * 64];
  __shared__ _Float16 Vl[2][64 * 64];
  const uint3 bi = xcd_swz();
  const int qb = bi.x;
  const int bh = bi.y;
  const int layer = bi.z;
  const int b = bh >> 4, h = bh & 15;
  const int q0 = qb * 128;
  const int tid = threadIdx.x;
  const int w = tid >> 6, lane = tid & 63;
  const int lr = lane & 15, hi = lane >> 4;
  const int qw = q0 + w * 32;

  const _Float16* Qp = qh + (size_t)layer * qs + (size_t)bh * SEQ * HD;
  const _Float16* Kp = kh + (size_t)layer * ks + (size_t)bh * SEQ * HD;
  const _Float16* Vp = vTp + (size_t)layer * vs + (size_t)bh * HD * SEQ;
  ob += (size_t)layer * os;

  f16x8 qf[2][2];
#pragma unroll
  for (int jq = 0; jq < 2; jq++)
#pragma unroll
    for (int ds = 0; ds < 2; ds++)
      qf[jq][ds] = *(const f16x8*)(Qp + (size_t)(qw + jq * 16 + lr) * HD + ds * 32 + hi * 8);

  float m[2] = {-1e30f, -1e30f}, l[2] = {0.f, 0.f};
  const f32x4 vz = {0.f, 0.f, 0.f, 0.f};
  f32x4 o[4][2];
#pragma unroll
  for (int dt = 0; dt < 4; dt++)
#pragma unroll
    for (int jq = 0; jq < 2; jq++) o[dt][jq] = vz;

  const int nst = CAUSAL ? ((q0 >> 6) + 2) : (SEQ / 64);

  auto stage = [&](int buf, int kt) {
    const int k0 = kt << 6;
#pragma unroll
    for (int c = 0; c < 2; c++) {
      int r = w * 16 + c * 8 + (lane >> 3);
      int cg = ((lane & 7) ^ (r & 7)) << 3;
      gld16(Kp + (size_t)(k0 + r) * HD + cg, &Kl[buf][(w * 16 + c * 8) * 64]);
      gld16(Vp + (size_t)r * SEQ + k0 + cg, &Vl[buf][(w * 16 + c * 8) * 64]);
    }
  };

  stage(0, 0);
  int cur = 0;
  for (int kt = 0; kt < nst; ++kt) {
    __syncthreads();
    if (kt + 1 < nst) stage(cur ^ 1, kt + 1);
    const int k0 = kt << 6;
    if (!CAUSAL || k0 <= qw + 31) {
      f32x4 s[4][2];
#pragma unroll
      for (int ik = 0; ik < 4; ik++)
#pragma unroll
        for (int jq = 0; jq < 2; jq++) s[ik][jq] = vz;
#pragma unroll
      for (int ds = 0; ds < 2; ds++) {
        f16x8 kf[4];
#pragma unroll
        for (int ik = 0; ik < 4; ik++) {
          int row = ik * 16 + lr;
          int off = (ds * 64 + hi * 16) ^ ((row & 7) << 4);
          kf[ik] = *(const f16x8*)((const char*)&Kl[cur][0] + row * 128 + off);
        }
        __builtin_amdgcn_s_setprio(1);
#pragma unroll
        for (int ik = 0; ik < 4; ik++)
#pragma unroll
          for (int jq = 0; jq < 2; jq++)
            s[ik][jq] = __builtin_amdgcn_mfma_f32_16x16x32_f16(kf[ik], qf[jq][ds], s[ik][jq], 0, 0, 0);
        __builtin_amdgcn_s_setprio(0);
      }
      float mx[2] = {-1e30f, -1e30f};
#pragma unroll
      for (int ik = 0; ik < 4; ik++)
#pragma unroll
        for (int jq = 0; jq < 2; jq++)
#pragma unroll
          for (int r = 0; r < 4; r++) {
            float v = s[ik][jq][r] * 0.03125f;
            if (CAUSAL) {
              int kk = k0 + ik * 16 + hi * 4 + r;
              int qq = qw + jq * 16 + lr;
              if (kk > qq) v = -1e30f;
            }
            s[ik][jq][r] = v;
            mx[jq] = fmaxf(mx[jq], v);
          }
      float sc[2], cs[2] = {0.f, 0.f};
      f16x4 pb[4][2];
#pragma unroll
      for (int jq = 0; jq < 2; jq++) {
        mx[jq] = fmaxf(mx[jq], __shfl_xor(mx[jq], 16, 64));
        mx[jq] = fmaxf(mx[jq], __shfl_xor(mx[jq], 32, 64));
        float mn = fmaxf(m[jq], mx[jq]);
        sc[jq] = __expf(m[jq] - mn);
        m[jq] = mn;
      }
#pragma unroll
      for (int ik = 0; ik < 4; ik++)
#pragma unroll
        for (int jq = 0; jq < 2; jq++)
#pragma unroll
          for (int r = 0; r < 4; r++) {
            float p = __expf(s[ik][jq][r] - m[jq]);
            cs[jq] += p;
            pb[ik][jq][r] = (_Float16)p;
          }
#pragma unroll
      for (int jq = 0; jq < 2; jq++) {
        float t = cs[jq];
        t += __shfl_xor(t, 16, 64);
        t += __shfl_xor(t, 32, 64);
        l[jq] = l[jq] * sc[jq] + t;
      }
#pragma unroll
      for (int dt = 0; dt < 4; dt++)
#pragma unroll
        for (int jq = 0; jq < 2; jq++)
#pragma unroll
          for (int r = 0; r < 4; r++) o[dt][jq][r] *= sc[jq];
#pragma unroll
      for (int ks2 = 0; ks2 < 4; ks2++) {
        f16x4 va[4];
#pragma unroll
        for (int dt = 0; dt < 4; dt++) {
          int row = dt * 16 + lr;
          int off = (ks2 * 32 + hi * 8) ^ ((row & 7) << 4);
          va[dt] = *(const f16x4*)((const char*)&Vl[cur][0] + row * 128 + off);
        }
        __builtin_amdgcn_s_setprio(1);
#pragma unroll
        for (int dt = 0; dt < 4; dt++)
#pragma unroll
          for (int jq = 0; jq < 2; jq++)
            o[dt][jq] = __builtin_amdgcn_mfma_f32_16x16x16f16(va[dt], pb[ks2][jq], o[dt][jq], 0, 0, 0);
        __builtin_amdgcn_s_setprio(0);
      }
    }
    cur ^= 1;
  }

  float inv[2] = {1.f / l[0], 1.f / l[1]};
#pragma unroll
  for (int jq = 0; jq < 2; jq++) {
    int q = qw + jq * 16 + lr;
    size_t rowoff = (size_t)(b * SEQ + q) * ESZ + h * 64;
#pragma unroll
    for (int dt = 0; dt < 4; dt++) {
      f16x4 ov;
#pragma unroll
      for (int r = 0; r < 4; r++) ov[r] = (_Float16)(o[dt][jq][r] * inv[jq]);
      *(f16x4*)(ob + rowoff + dt * 16 + hi * 4) = ov;
    }
  }
}

// ---------------------------------------------------------------------------
// Merged prep: weight convert+transpose + embedding/PE, one dispatch.
// LDS-free transpose, 8k x 8n per thread: 16 INDEPENDENT nontemporal f32x4
// loads (64 data VGPRs forces them all in flight -> latency-BW bound lifts),
// in-register transpose, 8x f16x8 stores (64B segments via kb lanes).
// NT loads: f32 weights are dead after this pass -- don't pollute L2/L3.
// ---------------------------------------------------------------------------
__device__ __forceinline__ void wtr2(const float* __restrict__ src,
                                     _Float16* __restrict__ dst,
                                     int K, int Ns, int k0, int n0, int tid)
{
  const int w = tid >> 6, lane = tid & 63;
  const int nb = lane & 15;          // 16 n-groups of 8
  const int kb = lane >> 4;          // 4 k-groups of 8
  const int kbase = k0 + w * 32 + kb * 8;
  const int nbase = n0 + nb * 8;
  f32x4 v[8], u[8];
#pragma unroll
  for (int i = 0; i < 8; i++) {
    const f32x4* p = (const f32x4*)(src + (size_t)(kbase + i) * Ns + nbase);
    v[i] = __builtin_nontemporal_load(p);
    u[i] = __builtin_nontemporal_load(p + 1);
  }
#pragma unroll
  for (int j = 0; j < 8; j++) {
    f16x8 o;
#pragma unroll
    for (int i = 0; i < 8; i++) {
      float f = (j < 4) ? v[i][j] : u[i][j - 4];
      o[i] = (_Float16)f;
    }
    *(f16x8*)(dst + (size_t)(nbase + j) * K + kbase) = o;
  }
}

struct W8 { const float* p[8]; };

__global__ __launch_bounds__(256)
void prep_k(W8 w8, const float* __restrict__ fW1, const float* __restrict__ fW2,
            _Float16* __restrict__ W16,
            const int* __restrict__ xt, const int* __restrict__ yt,
            const float* __restrict__ emb, const float* __restrict__ cls,
            float* __restrict__ y32, _Float16* __restrict__ y16,
            _Float16* __restrict__ x16)
{
  const size_t MM = (size_t)1 << 20;
  int idx = blockIdx.x;
  int tid = threadIdx.x;
  if (idx < 2048) {                   // 8 square weights x 4 layers, 64 tiles of 128x128
    int z = idx >> 6, rem = idx & 63;
    int widx = z >> 2, layer = z & 3;
    const float* src = w8.p[widx] + (size_t)layer * (ESZ * ESZ);
    _Float16* dst = W16 + (size_t)layer * 16 * MM + (size_t)widx * MM;
    wtr2(src, dst, 1024, 1024, (rem & 7) * 128, (rem >> 3) * 128, tid);
    return;
  }
  if (idx < 3072) {                   // fW1 [1024][4096] x 4: 8x32 tiles of 128x128
    int i = idx - 2048;
    int z = i >> 8, rem = i & 255;
    wtr2(fW1 + (size_t)z * ESZ * FFD, W16 + (size_t)z * 16 * MM + 8 * MM,
         1024, 4096, (rem & 7) * 128, (rem >> 3) * 128, tid);
    return;
  }
  if (idx < 4096) {                   // fW2 [4096][1024] x 4: 32x8 tiles of 128x128
    int i = idx - 3072;
    int z = i >> 8, rem = i & 255;
    wtr2(fW2 + (size_t)z * ESZ * FFD, W16 + (size_t)z * 16 * MM + 12 * MM,
         4096, 1024, (rem & 31) * 128, (rem >> 5) * 128, tid);
    return;
  }
  // ---- embedding + PE (quirk: pe row = batch index) ----
  int row = idx - 4096;
  bool isx = row < NB * SEQ;
  int rr = isx ? row : row - NB * SEQ;
  int b = rr >> 10, tpos = rr & (SEQ - 1);
  int col0 = tid * 4;
  float v[4];
  if (isx && tpos == SEQ - 1) {
#pragma unroll
    for (int j = 0; j < 4; j++) v[j] = cls[col0 + j];
  } else {
    int tok = isx ? xt[b * NXTOK + tpos] : yt[b * SEQ + tpos];
    const float* erow = emb + (size_t)tok * ESZ;
#pragma unroll
    for (int j = 0; j < 4; j++) {
      int e = col0 + j;
      float div = expf((float)(e & ~1) * (-9.210340371976184f / 1024.f));
      float ang = (float)b * div;
      float pe = (e & 1) ? cosf(ang) : sinf(ang);
      v[j] = erow[e] * 32.f + pe;
    }
  }
  size_t off = (size_t)rr * ESZ + col0;
  if (isx) {
#pragma unroll
    for (int j = 0; j < 4; j++) x16[off + j] = (_Float16)v[j];
  } else {
#pragma unroll
    for (int j = 0; j < 4; j++) { y32[off + j] = v[j]; y16[off + j] = (_Float16)v[j]; }
  }
}

// ---------------------------------------------------------------------------
// out = LN(a + sum of NP f16 partials)*g + b; writes f32 + f16.
// blockIdx.y = layer (batched): strides aStr/rStr/oStr/gStr.
// ---------------------------------------------------------------------------
template<int NP>
__global__ __launch_bounds__(256)
void lnres_k(const float* __restrict__ a, const _Float16* __restrict__ r0,
             const _Float16* __restrict__ r1, const _Float16* __restrict__ r2,
             const _Float16* __restrict__ r3,
             const float* __restrict__ g, const float* __restrict__ b,
             float* __restrict__ o32, _Float16* __restrict__ o16,
             long aStr, long rStr, long oStr, int gStr)
{
  int row = blockIdx.x;
  int lz = blockIdx.y;
  a += (size_t)lz * aStr;
  r0 += (size_t)lz * rStr;
  o32 += (size_t)lz * oStr;
  o16 += (size_t)lz * oStr;
  g += (size_t)lz * gStr;
  b += (size_t)lz * gStr;
  size_t off = (size_t)row * ESZ;
  int tid = threadIdx.x;
  float4 va = *(const float4*)(a + off + tid * 4);
  float x[4] = {va.x, va.y, va.z, va.w};
  {
    f16x4 v = *(const f16x4*)(r0 + off + tid * 4);
#pragma unroll
    for (int j = 0; j < 4; j++) x[j] += (float)v[j];
  }
  if (NP >= 2) {
    f16x4 v = *(const f16x4*)(r1 + off + tid * 4);
#pragma unroll
    for (int j = 0; j < 4; j++) x[j] += (float)v[j];
  }
  if (NP >= 4) {
    f16x4 v = *(const f16x4*)(r2 + off + tid * 4);
    f16x4 u = *(const f16x4*)(r3 + off + tid * 4);
#pragma unroll
    for (int j = 0; j < 4; j++) x[j] += (float)v[j] + (float)u[j];
  }
  float s = x[0] + x[1] + x[2] + x[3];
  float s2 = x[0] * x[0] + x[1] * x[1] + x[2] * x[2] + x[3] * x[3];
  for (int o = 32; o > 0; o >>= 1) {
    s += __shfl_xor(s, o, 64);
    s2 += __shfl_xor(s2, o, 64);
  }
  __shared__ float rs[4], rs2[4];
  if ((tid & 63) == 0) { rs[tid >> 6] = s; rs2[tid >> 6] = s2; }
  __syncthreads();
  s = rs[0] + rs[1] + rs[2] + rs[3];
  s2 = rs2[0] + rs2[1] + rs2[2] + rs2[3];
  float mean = s * (1.f / ESZ);
  float var = s2 * (1.f / ESZ) - mean * mean;
  float inv = 1.f / sqrtf(var + LNEPS);
  float4 vo;
#pragma unroll
  for (int j = 0; j < 4; j++) {
    int c = tid * 4 + j;
    float o = (x[j] - mean) * inv * g[c] + b[c];
    ((float*)&vo)[j] = o;
    o16[off + c] = (_Float16)o;
  }
  *(float4*)(o32 + off + tid * 4) = vo;
}

// ---------------------------------------------------------------------------

template<int BM, int BN, int EPI, bool RELU, int SPLITK>
static void gemm(hipStream_t st, const _Float16* A, const _Float16* B,
                 const float* b0, const float* b1, const float* b2,
                 void* C0, void* C1, int M, int N, int K,
                 int lda, int ldb, int ldc,
                 int Z, long sAz, long sBz, int cdiv, long sC1, long sC2,
                 int vseg, int bstr)
{
  dim3 g(M / BM, N / BN, Z);
  gemm_k<BM, BN, EPI, RELU, SPLITK><<<g, dim3(256), 0, st>>>(
      A, B, b0, b1, b2, C0, C1, K, lda, ldb, ldc, sAz, sBz, cdiv, sC1, sC2, vseg, bstr);
}

extern "C" void kernel_launch(void* const* d_in, const int* in_sizes, int n_in,
                              void* d_out, int out_size, void* d_ws, size_t ws_size,
                              hipStream_t stream) {
  (void)n_in; (void)out_size; (void)ws_size;
  const float *emb, *cls, *sWq, *sbq, *sWk, *sbk, *sWv, *sbv, *sWo, *sbo;
  const float *cWq, *cbq, *cWk, *cbk, *cWv, *cbv, *cWo, *cbo;
  const float *fW1, *fb1, *fW2, *fb2, *g1, *g2, *g3, *b1, *b2, *b3;
  const int *xt, *yt;
  if (in_sizes[0] == NB * NXTOK) {
    xt = (const int*)d_in[0]; yt = (const int*)d_in[1];
    emb = (const float*)d_in[2]; cls = (const float*)d_in[3];
    sWq = (const float*)d_in[4]; sbq = (const float*)d_in[5];
    sWk = (const float*)d_in[6]; sbk = (const float*)d_in[7];
    sWv = (const float*)d_in[8]; sbv = (const float*)d_in[9];
    sWo = (const float*)d_in[10]; sbo = (const float*)d_in[11];
    cWq = (const float*)d_in[12]; cbq = (const float*)d_in[13];
    cWk = (const float*)d_in[14]; cbk = (const float*)d_in[15];
    cWv = (const float*)d_in[16]; cbv = (const float*)d_in[17];
    cWo = (const float*)d_in[18]; cbo = (const float*)d_in[19];
    g1 = (const float*)d_in[20]; b1 = (const float*)d_in[21];
    g2 = (const float*)d_in[22]; b2 = (const float*)d_in[23];
    g3 = (const float*)d_in[24]; b3 = (const float*)d_in[25];
    fW1 = (const float*)d_in[26]; fb1 = (const float*)d_in[27];
    fW2 = (const float*)d_in[28]; fb2 = (const float*)d_in[29];
  } else {
    emb = (const float*)d_in[0]; cls = (const float*)d_in[1];
    sWq = (const float*)d_in[2]; sbq = (const float*)d_in[3];
    sWk = (const float*)d_in[4]; sbk = (const float*)d_in[5];
    sWv = (const float*)d_in[6]; sbv = (const float*)d_in[7];
    sWo = (const float*)d_in[8]; sbo = (const float*)d_in[9];
    cWq = (const float*)d_in[10]; cbq = (const float*)d_in[11];
    cWk = (const float*)d_in[12]; cbk = (const float*)d_in[13];
    cWv = (const float*)d_in[14]; cbv = (const float*)d_in[15];
    cWo = (const float*)d_in[16]; cbo = (const float*)d_in[17];
    fW1 = (const float*)d_in[18]; fb1 = (const float*)d_in[19];
    fW2 = (const float*)d_in[20]; fb2 = (const float*)d_in[21];
    g1 = (const float*)d_in[22]; g2 = (const float*)d_in[23]; g3 = (const float*)d_in[24];
    b1 = (const float*)d_in[25]; b2 = (const float*)d_in[26]; b3 = (const float*)d_in[27];
    xt = (const int*)d_in[28]; yt = (const int*)d_in[29];
  }

  // ---- ws layout ----
  const size_t MM = (size_t)1 << 20;
  _Float16* W16 = (_Float16*)d_ws;       // weights: 64 MM f16 (4 layers x 16 MM)
  _Float16* qhk_all = W16 + 64 * MM;     // [l]{q 2MM, k 2MM} = 16 MM
  _Float16* vT_all  = W16 + 80 * MM;     // [l] 2MM = 8 MM
  _Float16* ob_all  = W16 + 88 * MM;     // [l] 2MM = 8 MM
  _Float16* y16     = W16 + 96 * MM;     // 2 MM
  _Float16* yl16_all= W16 + 98 * MM;     // [l] 2MM = 8 MM
  _Float16* cqh_all = W16 + 106 * MM;    // [l] 2MM = 8 MM
  _Float16* kh_c    = W16 + 114 * MM;    // 2 MM
  _Float16* vT_c    = W16 + 116 * MM;    // 2 MM
  _Float16* ob_c    = W16 + 118 * MM;    // 2 MM
  _Float16* x16     = W16 + 120 * MM;    // 2 MM
  _Float16* ffn     = W16 + 122 * MM;    // 8 MM
  float* y32      = (float*)(W16 + 130 * MM);  // 2 MM f32
  _Float16* tmp16 = (_Float16*)(y32 + 2 * MM); // 4 x 2MM f16 partials
  float* yl32_all = y32 + 10 * MM;             // 4 x 2MM f32
  float* x32      = y32 + 18 * MM;             // 2 MM f32
  const long SP16 = 2048L * 1024;              // 2MM f16 partial/layer stride

  // ---- upfront: merged weight conversion + embed (1 dispatch) ----
  W8 w8;
  w8.p[0] = sWq; w8.p[1] = sWk; w8.p[2] = sWv; w8.p[3] = cWq;
  w8.p[4] = cWk; w8.p[5] = cWv; w8.p[6] = sWo; w8.p[7] = cWo;
  prep_k<<<dim3(8192), 256, 0, stream>>>(w8, fW1, fW2, W16, xt, yt, emb, cls,
                                         y32, y16, x16);

  // ---- hoisted: entire self-attn branch + cross-q for ALL layers ----
  gemm<128, 128, 2, false, 1>(stream, y16, W16, sbq, sbk, sbv,
      qhk_all, vT_all, 2048, 3072, 1024, 1024, 1024, 0,
      4, 0, 16 * MM, 1, 4 * MM, 2 * MM, 2, 1024);
  flash_k<true><<<dim3(8, 32, 4), 256, 0, stream>>>(
      qhk_all, qhk_all + 2 * MM, vT_all, ob_all, 4 * MM, 4 * MM, 2 * MM, 2 * MM);
  gemm<128, 128, 1, false, 1>(stream, ob_all, W16 + 6 * MM, sbo, nullptr, nullptr,
      tmp16, nullptr, 2048, 1024, 1024, 1024, 1024, 1024,
      4, 2 * MM, 16 * MM, 1, SP16, 0, 0, 1024);
  lnres_k<1><<<dim3(2048, 4), 256, 0, stream>>>(y32, tmp16, nullptr, nullptr, nullptr,
      g1, b1, yl32_all, yl16_all, 0, SP16, 2 * MM, 1024);
  gemm<128, 128, 2, false, 1>(stream, yl16_all, W16 + 3 * MM, cbq, nullptr, nullptr,
      cqh_all, nullptr, 2048, 1024, 1024, 1024, 1024, 0,
      4, 2 * MM, 16 * MM, 1, 2 * MM, 0, 3, 1024);

  // ---- sequential decoder chain ----
  for (int l = 0; l < NLAYER; l++) {
    _Float16* wl   = W16 + (size_t)l * 16 * MM;
    _Float16* wckv = wl + 4 * MM;
    _Float16* wco  = wl + 7 * MM;
    _Float16* wf1  = wl + 8 * MM;
    _Float16* wf2  = wl + 12 * MM;

    gemm<128, 128, 2, false, 1>(stream, x16, wckv, cbk + l * ESZ, cbv + l * ESZ,
        nullptr, kh_c, vT_c, 2048, 2048, 1024, 1024, 1024, 0,
        1, 0, 0, 1, 0, 0, 1, 0);
    flash_k<false><<<dim3(8, 32, 1), 256, 0, stream>>>(
        cqh_all + (size_t)l * 2 * MM, kh_c, vT_c, ob_c, 0, 0, 0, 0);
    gemm<128, 128, 1, false, 4>(stream, ob_c, wco, cbo + l * ESZ, nullptr, nullptr,
        tmp16, nullptr, 2048, 1024, 1024, 1024, 1024, 1024,
        4, 0, 0, 1, SP16, 0, 0, 0);
    lnres_k<4><<<dim3(2048, 1), 256, 0, stream>>>(yl32_all + (size_t)l * 2 * MM,
        tmp16, tmp16 + SP16, tmp16 + 2 * SP16, tmp16 + 3 * SP16,
        g2 + l * ESZ, b2 + l * ESZ, x32, x16, 0, 0, 0, 0);

    gemm<128, 128, 1, true, 1>(stream, x16, wf1, fb1 + l * FFD, nullptr, nullptr,
        ffn, nullptr, 2048, 4096, 1024, 1024, 1024, 4096,
        1, 0, 0, 1, 0, 0, 0, 0);
    gemm<128, 128, 1, false, 4>(stream, ffn, wf2, fb2 + l * ESZ, nullptr, nullptr,
        tmp16, nullptr, 2048, 1024, 4096, 4096, 4096, 1024,
        4, 0, 0, 1, SP16, 0, 0, 0);
    lnres_k<4><<<dim3(2048, 1), 256, 0, stream>>>(x32, tmp16, tmp16 + SP16,
        tmp16 + 2 * SP16, tmp16 + 3 * SP16, g3 + l * ESZ, b3 + l * ESZ,
        (l == NLAYER - 1) ? (float*)d_out : x32, x16, 0, 0, 0, 0);
  }
}

// Round 15
// 800.478 us; speedup vs baseline: 1.1538x; 1.1538x over previous
//
#include <hip/hip_runtime.h>
#include <cstdint>

#define ESZ 1024
#define NH 16
#define HD 64
#define NLAYER 4
#define FFD 4096
#define NB 2
#define NXTOK 1023
#define SEQ 1024
#define LNEPS 1e-5f

typedef __attribute__((ext_vector_type(8))) _Float16 f16x8;
typedef __attribute__((ext_vector_type(4))) _Float16 f16x4;
typedef __attribute__((ext_vector_type(4))) float f32x4;

__device__ __forceinline__ void gld16(const void* g, void* l) {
  __builtin_amdgcn_global_load_lds(
      (const __attribute__((address_space(1))) unsigned int*)g,
      (__attribute__((address_space(3))) unsigned int*)l, 16, 0, 0);
}

// Bijective XCD-aware block swizzle (each XCD gets a contiguous work chunk).
__device__ __forceinline__ uint3 xcd_swz() {
  unsigned gx = gridDim.x, gy = gridDim.y;
  unsigned nwg = gx * gy * gridDim.z;
  unsigned lin = (blockIdx.z * gy + blockIdx.y) * gx + blockIdx.x;
  unsigned q = nwg >> 3, r = nwg & 7;
  unsigned xcd = lin & 7, idx = lin >> 3;
  unsigned wid = (xcd < r ? xcd * (q + 1) : r * (q + 1) + (xcd - r) * q) + idx;
  uint3 o;
  o.x = wid % gx;
  unsigned t = wid / gx;
  o.y = t % gy;
  o.z = t / gy;
  return o;
}

// ---------------------------------------------------------------------------
// Shared GEMM epilogue (non-V blocks). EPI: 0 f32, 1 f16, 2 QKV head scatter.
// ---------------------------------------------------------------------------
template<int MI, int NJ, int EPI, bool RELU, int SPLITK>
__device__ __forceinline__ void gemm_epi(
    f32x4 (&acc)[MI][NJ], int m0, int n0, int wr, int wc, int lr, int hi,
    int z, size_t coff, int ldc,
    const float* bias0, const float* bias1, const float* bias2, int bstr,
    void* C0, void* C1, long sC1, long sC2, int vseg)
{
  const int rb = hi * 4;
#pragma unroll
  for (int j = 0; j < NJ; j++) {
    const int n = n0 + wc + j * 16 + lr;
    float bv = 0.f;
    if (EPI == 2) {
      int seg = n >> 10;
      const float* bp = (seg == 0) ? bias0 : ((seg == 1) ? bias1 : bias2);
      bv = bp[bstr * z + (n & 1023)];
    } else if (bias0) bv = bias0[bstr * z + n];
    if (SPLITK > 1 && z > 0) bv = 0.f;
#pragma unroll
    for (int i = 0; i < MI; i++) {
#pragma unroll
      for (int r = 0; r < 4; r++) {
        int row = m0 + wr + i * 16 + rb + r;
        float out = acc[i][j][r] + bv;
        if (RELU) out = fmaxf(out, 0.f);
        if (EPI == 0) {
          ((float*)C0)[coff + (size_t)row * ldc + n] = out;
        } else if (EPI == 1) {
          ((_Float16*)C0)[coff + (size_t)row * ldc + n] = (_Float16)out;
        } else {
          int seg = n >> 10, n1 = n & 1023, h = n1 >> 6, d = n1 & 63;
          int b = row >> 10, s = row & 1023;
          if (seg == vseg)
            ((_Float16*)C1)[(size_t)z * sC2 + (((size_t)b * NH + h) * HD + d) * SEQ + s] = (_Float16)out;
          else
            ((_Float16*)C0)[(size_t)z * sC1 + (size_t)seg * ((size_t)NB * NH * SEQ * HD)
                            + (((size_t)b * NH + h) * SEQ + s) * HD + d] = (_Float16)out;
        }
      }
    }
  }
}

// ---------------------------------------------------------------------------
// 4-wave NT MFMA GEMM, BM=BN=128, BK=64, DOUBLE-buffered 64 KB LDS.
// Grids here are 128-512 blocks on 256 CUs (~1 block/CU), so inter-block
// overlap (m97's lever) is unavailable -- the T3 minimum 2-phase pipeline
// (issue next tile's gld16 after the barrier, compute current) supplies the
// overlap instead. 8-row XOR swizzle (128B rows) -> 0 bank conflicts.
// EPI==2 V-blocks: LDS-transpose epilogue -> coalesced f16x8 V^T stores.
// ---------------------------------------------------------------------------
template<int BM, int BN, int EPI, bool RELU, int SPLITK>
__global__ __launch_bounds__(256)
void gemm_k(const _Float16* __restrict__ A, const _Float16* __restrict__ Bm,
            const float* __restrict__ bias0, const float* __restrict__ bias1,
            const float* __restrict__ bias2,
            void* __restrict__ C0, void* __restrict__ C1,
            int K, int lda, int ldb, int ldc,
            long sAz, long sBz, int cdiv, long sC1, long sC2, int vseg, int bstr)
{
  constexpr int MI = BM / 32, NJ = BN / 32;
  constexpr int DBUF = 2 * (BM + BN) * 64;            // f16 elems (64 KB)
  constexpr int TBUF = (EPI == 2) ? 128 * 136 : 0;
  constexpr int LDSN = (TBUF > DBUF) ? TBUF : DBUF;
  __shared__ _Float16 lds[LDSN];

  const uint3 bi = xcd_swz();
  const int m0 = bi.x * BM;
  const int n0 = bi.y * BN;
  const int z = bi.z;
  const _Float16* Ab;
  const _Float16* Bb;
  size_t coff;
  if (SPLITK > 1) {
    int koff = z * (K / SPLITK);
    Ab = A + koff;
    Bb = Bm + koff;
    coff = (size_t)z * sC1;
  } else {
    Ab = A + (size_t)z * sAz;
    Bb = Bm + (size_t)z * sBz;
    coff = (size_t)(z / cdiv) * sC1 + (size_t)(z % cdiv) * sC2;
  }
  const int tid = threadIdx.x;
  const int lane = tid & 63;
  const int w = tid >> 6;
  const int lr = lane & 15;
  const int hi = lane >> 4;
  const int wr = (w >> 1) * (BM / 2);
  const int wc = (w & 1) * (BN / 2);

  const f32x4 vz = {0.f, 0.f, 0.f, 0.f};
  f32x4 acc[MI][NJ];
#pragma unroll
  for (int i = 0; i < MI; i++)
#pragma unroll
    for (int j = 0; j < NJ; j++) acc[i][j] = vz;

  const int nk = (K / SPLITK) >> 6;

  auto stage = [&](int buf, int kt) {
    const int k0 = kt << 6;
    _Float16* Ah = lds + buf * (BM * 64);
    _Float16* Bh = lds + 2 * (BM * 64) + buf * (BN * 64);
#pragma unroll
    for (int c = 0; c < MI; c++) {
      int r = w * (BM / 4) + c * 8 + (lane >> 3);
      int cg = ((lane & 7) ^ (r & 7)) << 3;
      gld16(Ab + (size_t)(m0 + r) * lda + k0 + cg, Ah + (w * (BM / 4) + c * 8) * 64);
    }
#pragma unroll
    for (int c = 0; c < NJ; c++) {
      int r = w * (BN / 4) + c * 8 + (lane >> 3);
      int cg = ((lane & 7) ^ (r & 7)) << 3;
      gld16(Bb + (size_t)(n0 + r) * ldb + k0 + cg, Bh + (w * (BN / 4) + c * 8) * 64);
    }
  };

  stage(0, 0);
  int cur = 0;
  for (int kt = 0; kt < nk; ++kt) {
    __syncthreads();   // drains vmcnt for buf[cur] loads, syncs prev compute
    if (kt + 1 < nk) stage(cur ^ 1, kt + 1);
    const char* Ah = (const char*)(lds + cur * (BM * 64));
    const char* Bh = (const char*)(lds + 2 * (BM * 64) + cur * (BN * 64));
#pragma unroll
    for (int kk = 0; kk < 2; kk++) {
      f16x8 af[MI], bf[NJ];
#pragma unroll
      for (int i = 0; i < MI; i++) {
        int row = wr + i * 16 + lr;
        int off = ((kk << 6) | (hi << 4)) ^ ((row & 7) << 4);
        af[i] = *(const f16x8*)(Ah + row * 128 + off);
      }
#pragma unroll
      for (int j = 0; j < NJ; j++) {
        int row = wc + j * 16 + lr;
        int off = ((kk << 6) | (hi << 4)) ^ ((row & 7) << 4);
        bf[j] = *(const f16x8*)(Bh + row * 128 + off);
      }
#pragma unroll
      for (int i = 0; i < MI; i++)
#pragma unroll
        for (int j = 0; j < NJ; j++)
          acc[i][j] = __builtin_amdgcn_mfma_f32_16x16x32_f16(af[i], bf[j], acc[i][j], 0, 0, 0);
    }
    cur ^= 1;
  }

  if (EPI == 2 && (n0 >> 10) == vseg) {
    __syncthreads();
    _Float16* T = lds;   // [128][136]
    const float* bp = (vseg == 0) ? bias0 : ((vseg == 1) ? bias1 : bias2);
#pragma unroll
    for (int j = 0; j < NJ; j++) {
      int nloc = wc + j * 16 + lr;
      float bv = bp[bstr * z + ((n0 + nloc) & 1023)];
#pragma unroll
      for (int i = 0; i < MI; i++) {
        f16x4 tv;
#pragma unroll
        for (int r = 0; r < 4; r++) tv[r] = (_Float16)(acc[i][j][r] + bv);
        *(f16x4*)(T + nloc * 136 + wr + i * 16 + hi * 4) = tv;
      }
    }
    __syncthreads();
    int rowT = tid >> 1;
    int c0 = (tid & 1) << 6;
    int nn = (n0 & 1023) + rowT;
    int h = nn >> 6, d = nn & 63;
    int bb = m0 >> 10;
    int s0 = (m0 & 1023) + c0;
    _Float16* dst = (_Float16*)C1 + (size_t)z * sC2
                  + (((size_t)bb * NH + h) * HD + d) * SEQ + s0;
    const _Float16* src = T + rowT * 136 + c0;
#pragma unroll
    for (int t2 = 0; t2 < 8; t2++)
      *(f16x8*)(dst + t2 * 8) = *(const f16x8*)(src + t2 * 8);
    return;
  }

  gemm_epi<MI, NJ, EPI, RELU, SPLITK>(acc, m0, n0, wr, wc, lr, hi, z, coff, ldc,
                                      bias0, bias1, bias2, bstr, C0, C1, sC1, sC2, vseg);
}

// ---------------------------------------------------------------------------
// Flash attention: one block = 128 q rows of one (b,h); 4 waves x 32 q rows.
// blockIdx.z = layer. Swapped QK^T; S^T C-layout IS the B-fragment of
// mfma_16x16x16_f16 so PV needs no P relayout. setprio around MFMA clusters.
// ---------------------------------------------------------------------------
template<bool CAUSAL>
__global__ __launch_bounds__(256)
void flash_k(const _Float16* __restrict__ qh, const _Float16* __restrict__ kh,
             const _Float16* __restrict__ vTp, _Float16* __restrict__ ob,
             long qs, long ks, long vs, long os)
{
  __shared__ _Float16 Kl[2][64 * 64];
  __shared__ _Float16 Vl[2][64 * 64];
  const uint3 bi = xcd_swz();
  const int qb = bi.x;
  const int bh = bi.y;
  const int layer = bi.z;
  const int b = bh >> 4, h = bh & 15;
  const int q0 = qb * 128;
  const int tid = threadIdx.x;
  const int w = tid >> 6, lane = tid & 63;
  const int lr = lane & 15, hi = lane >> 4;
  const int qw = q0 + w * 32;

  const _Float16* Qp = qh + (size_t)layer * qs + (size_t)bh * SEQ * HD;
  const _Float16* Kp = kh + (size_t)layer * ks + (size_t)bh * SEQ * HD;
  const _Float16* Vp = vTp + (size_t)layer * vs + (size_t)bh * HD * SEQ;
  ob += (size_t)layer * os;

  f16x8 qf[2][2];
#pragma unroll
  for (int jq = 0; jq < 2; jq++)
#pragma unroll
    for (int ds = 0; ds < 2; ds++)
      qf[jq][ds] = *(const f16x8*)(Qp + (size_t)(qw + jq * 16 + lr) * HD + ds * 32 + hi * 8);

  float m[2] = {-1e30f, -1e30f}, l[2] = {0.f, 0.f};
  const f32x4 vz = {0.f, 0.f, 0.f, 0.f};
  f32x4 o[4][2];
#pragma unroll
  for (int dt = 0; dt < 4; dt++)
#pragma unroll
    for (int jq = 0; jq < 2; jq++) o[dt][jq] = vz;

  const int nst = CAUSAL ? ((q0 >> 6) + 2) : (SEQ / 64);

  auto stage = [&](int buf, int kt) {
    const int k0 = kt << 6;
#pragma unroll
    for (int c = 0; c < 2; c++) {
      int r = w * 16 + c * 8 + (lane >> 3);
      int cg = ((lane & 7) ^ (r & 7)) << 3;
      gld16(Kp + (size_t)(k0 + r) * HD + cg, &Kl[buf][(w * 16 + c * 8) * 64]);
      gld16(Vp + (size_t)r * SEQ + k0 + cg, &Vl[buf][(w * 16 + c * 8) * 64]);
    }
  };

  stage(0, 0);
  int cur = 0;
  for (int kt = 0; kt < nst; ++kt) {
    __syncthreads();
    if (kt + 1 < nst) stage(cur ^ 1, kt + 1);
    const int k0 = kt << 6;
    if (!CAUSAL || k0 <= qw + 31) {
      f32x4 s[4][2];
#pragma unroll
      for (int ik = 0; ik < 4; ik++)
#pragma unroll
        for (int jq = 0; jq < 2; jq++) s[ik][jq] = vz;
#pragma unroll
      for (int ds = 0; ds < 2; ds++) {
        f16x8 kf[4];
#pragma unroll
        for (int ik = 0; ik < 4; ik++) {
          int row = ik * 16 + lr;
          int off = (ds * 64 + hi * 16) ^ ((row & 7) << 4);
          kf[ik] = *(const f16x8*)((const char*)&Kl[cur][0] + row * 128 + off);
        }
        __builtin_amdgcn_s_setprio(1);
#pragma unroll
        for (int ik = 0; ik < 4; ik++)
#pragma unroll
          for (int jq = 0; jq < 2; jq++)
            s[ik][jq] = __builtin_amdgcn_mfma_f32_16x16x32_f16(kf[ik], qf[jq][ds], s[ik][jq], 0, 0, 0);
        __builtin_amdgcn_s_setprio(0);
      }
      float mx[2] = {-1e30f, -1e30f};
#pragma unroll
      for (int ik = 0; ik < 4; ik++)
#pragma unroll
        for (int jq = 0; jq < 2; jq++)
#pragma unroll
          for (int r = 0; r < 4; r++) {
            float v = s[ik][jq][r] * 0.03125f;
            if (CAUSAL) {
              int kk = k0 + ik * 16 + hi * 4 + r;
              int qq = qw + jq * 16 + lr;
              if (kk > qq) v = -1e30f;
            }
            s[ik][jq][r] = v;
            mx[jq] = fmaxf(mx[jq], v);
          }
      float sc[2], cs[2] = {0.f, 0.f};
      f16x4 pb[4][2];
#pragma unroll
      for (int jq = 0; jq < 2; jq++) {
        mx[jq] = fmaxf(mx[jq], __shfl_xor(mx[jq], 16, 64));
        mx[jq] = fmaxf(mx[jq], __shfl_xor(mx[jq], 32, 64));
        float mn = fmaxf(m[jq], mx[jq]);
        sc[jq] = __expf(m[jq] - mn);
        m[jq] = mn;
      }
#pragma unroll
      for (int ik = 0; ik < 4; ik++)
#pragma unroll
        for (int jq = 0; jq < 2; jq++)
#pragma unroll
          for (int r = 0; r < 4; r++) {
            float p = __expf(s[ik][jq][r] - m[jq]);
            cs[jq] += p;
            pb[ik][jq][r] = (_Float16)p;
          }
#pragma unroll
      for (int jq = 0; jq < 2; jq++) {
        float t = cs[jq];
        t += __shfl_xor(t, 16, 64);
        t += __shfl_xor(t, 32, 64);
        l[jq] = l[jq] * sc[jq] + t;
      }
#pragma unroll
      for (int dt = 0; dt < 4; dt++)
#pragma unroll
        for (int jq = 0; jq < 2; jq++)
#pragma unroll
          for (int r = 0; r < 4; r++) o[dt][jq][r] *= sc[jq];
#pragma unroll
      for (int ks2 = 0; ks2 < 4; ks2++) {
        f16x4 va[4];
#pragma unroll
        for (int dt = 0; dt < 4; dt++) {
          int row = dt * 16 + lr;
          int off = (ks2 * 32 + hi * 8) ^ ((row & 7) << 4);
          va[dt] = *(const f16x4*)((const char*)&Vl[cur][0] + row * 128 + off);
        }
        __builtin_amdgcn_s_setprio(1);
#pragma unroll
        for (int dt = 0; dt < 4; dt++)
#pragma unroll
          for (int jq = 0; jq < 2; jq++)
            o[dt][jq] = __builtin_amdgcn_mfma_f32_16x16x16f16(va[dt], pb[ks2][jq], o[dt][jq], 0, 0, 0);
        __builtin_amdgcn_s_setprio(0);
      }
    }
    cur ^= 1;
  }

  float inv[2] = {1.f / l[0], 1.f / l[1]};
#pragma unroll
  for (int jq = 0; jq < 2; jq++) {
    int q = qw + jq * 16 + lr;
    size_t rowoff = (size_t)(b * SEQ + q) * ESZ + h * 64;
#pragma unroll
    for (int dt = 0; dt < 4; dt++) {
      f16x4 ov;
#pragma unroll
      for (int r = 0; r < 4; r++) ov[r] = (_Float16)(o[dt][jq][r] * inv[jq]);
      *(f16x4*)(ob + rowoff + dt * 16 + hi * 4) = ov;
    }
  }
}

// ---------------------------------------------------------------------------
// Merged prep: weight convert+transpose + embedding/PE, one dispatch.
// LDS-free transpose, 8k x 8n per thread, PLAIN loads (NT loads bypassed
// L2/L3 and raised FETCH 139->238 MB in R14 -- reverted).
// ---------------------------------------------------------------------------
__device__ __forceinline__ void wtr2(const float* __restrict__ src,
                                     _Float16* __restrict__ dst,
                                     int K, int Ns, int k0, int n0, int tid)
{
  const int w = tid >> 6, lane = tid & 63;
  const int nb = lane & 15;
  const int kb = lane >> 4;
  const int kbase = k0 + w * 32 + kb * 8;
  const int nbase = n0 + nb * 8;
  f32x4 v[8], u[8];
#pragma unroll
  for (int i = 0; i < 8; i++) {
    const f32x4* p = (const f32x4*)(src + (size_t)(kbase + i) * Ns + nbase);
    v[i] = p[0];
    u[i] = p[1];
  }
#pragma unroll
  for (int j = 0; j < 8; j++) {
    f16x8 o;
#pragma unroll
    for (int i = 0; i < 8; i++) {
      float f = (j < 4) ? v[i][j] : u[i][j - 4];
      o[i] = (_Float16)f;
    }
    *(f16x8*)(dst + (size_t)(nbase + j) * K + kbase) = o;
  }
}

struct W8 { const float* p[8]; };

__global__ __launch_bounds__(256)
void prep_k(W8 w8, const float* __restrict__ fW1, const float* __restrict__ fW2,
            _Float16* __restrict__ W16,
            const int* __restrict__ xt, const int* __restrict__ yt,
            const float* __restrict__ emb, const float* __restrict__ cls,
            float* __restrict__ y32, _Float16* __restrict__ y16,
            _Float16* __restrict__ x16)
{
  const size_t MM = (size_t)1 << 20;
  int idx = blockIdx.x;
  int tid = threadIdx.x;
  if (idx < 2048) {
    int z = idx >> 6, rem = idx & 63;
    int widx = z >> 2, layer = z & 3;
    const float* src = w8.p[widx] + (size_t)layer * (ESZ * ESZ);
    _Float16* dst = W16 + (size_t)layer * 16 * MM + (size_t)widx * MM;
    wtr2(src, dst, 1024, 1024, (rem & 7) * 128, (rem >> 3) * 128, tid);
    return;
  }
  if (idx < 3072) {
    int i = idx - 2048;
    int z = i >> 8, rem = i & 255;
    wtr2(fW1 + (size_t)z * ESZ * FFD, W16 + (size_t)z * 16 * MM + 8 * MM,
         1024, 4096, (rem & 7) * 128, (rem >> 3) * 128, tid);
    return;
  }
  if (idx < 4096) {
    int i = idx - 3072;
    int z = i >> 8, rem = i & 255;
    wtr2(fW2 + (size_t)z * ESZ * FFD, W16 + (size_t)z * 16 * MM + 12 * MM,
         4096, 1024, (rem & 31) * 128, (rem >> 5) * 128, tid);
    return;
  }
  int row = idx - 4096;
  bool isx = row < NB * SEQ;
  int rr = isx ? row : row - NB * SEQ;
  int b = rr >> 10, tpos = rr & (SEQ - 1);
  int col0 = tid * 4;
  float v[4];
  if (isx && tpos == SEQ - 1) {
#pragma unroll
    for (int j = 0; j < 4; j++) v[j] = cls[col0 + j];
  } else {
    int tok = isx ? xt[b * NXTOK + tpos] : yt[b * SEQ + tpos];
    const float* erow = emb + (size_t)tok * ESZ;
#pragma unroll
    for (int j = 0; j < 4; j++) {
      int e = col0 + j;
      float div = expf((float)(e & ~1) * (-9.210340371976184f / 1024.f));
      float ang = (float)b * div;
      float pe = (e & 1) ? cosf(ang) : sinf(ang);
      v[j] = erow[e] * 32.f + pe;
    }
  }
  size_t off = (size_t)rr * ESZ + col0;
  if (isx) {
#pragma unroll
    for (int j = 0; j < 4; j++) x16[off + j] = (_Float16)v[j];
  } else {
#pragma unroll
    for (int j = 0; j < 4; j++) { y32[off + j] = v[j]; y16[off + j] = (_Float16)v[j]; }
  }
}

// ---------------------------------------------------------------------------
// out = LN(a + sum of NP f16 partials)*g + b; writes f32 + f16.
// blockIdx.y = layer (batched): strides aStr/rStr/oStr/gStr.
// ---------------------------------------------------------------------------
template<int NP>
__global__ __launch_bounds__(256)
void lnres_k(const float* __restrict__ a, const _Float16* __restrict__ r0,
             const _Float16* __restrict__ r1, const _Float16* __restrict__ r2,
             const _Float16* __restrict__ r3,
             const float* __restrict__ g, const float* __restrict__ b,
             float* __restrict__ o32, _Float16* __restrict__ o16,
             long aStr, long rStr, long oStr, int gStr)
{
  int row = blockIdx.x;
  int lz = blockIdx.y;
  a += (size_t)lz * aStr;
  r0 += (size_t)lz * rStr;
  o32 += (size_t)lz * oStr;
  o16 += (size_t)lz * oStr;
  g += (size_t)lz * gStr;
  b += (size_t)lz * gStr;
  size_t off = (size_t)row * ESZ;
  int tid = threadIdx.x;
  float4 va = *(const float4*)(a + off + tid * 4);
  float x[4] = {va.x, va.y, va.z, va.w};
  {
    f16x4 v = *(const f16x4*)(r0 + off + tid * 4);
#pragma unroll
    for (int j = 0; j < 4; j++) x[j] += (float)v[j];
  }
  if (NP >= 2) {
    f16x4 v = *(const f16x4*)(r1 + off + tid * 4);
#pragma unroll
    for (int j = 0; j < 4; j++) x[j] += (float)v[j];
  }
  if (NP >= 4) {
    f16x4 v = *(const f16x4*)(r2 + off + tid * 4);
    f16x4 u = *(const f16x4*)(r3 + off + tid * 4);
#pragma unroll
    for (int j = 0; j < 4; j++) x[j] += (float)v[j] + (float)u[j];
  }
  float s = x[0] + x[1] + x[2] + x[3];
  float s2 = x[0] * x[0] + x[1] * x[1] + x[2] * x[2] + x[3] * x[3];
  for (int o = 32; o > 0; o >>= 1) {
    s += __shfl_xor(s, o, 64);
    s2 += __shfl_xor(s2, o, 64);
  }
  __shared__ float rs[4], rs2[4];
  if ((tid & 63) == 0) { rs[tid >> 6] = s; rs2[tid >> 6] = s2; }
  __syncthreads();
  s = rs[0] + rs[1] + rs[2] + rs[3];
  s2 = rs2[0] + rs2[1] + rs2[2] + rs2[3];
  float mean = s * (1.f / ESZ);
  float var = s2 * (1.f / ESZ) - mean * mean;
  float inv = 1.f / sqrtf(var + LNEPS);
  float4 vo;
#pragma unroll
  for (int j = 0; j < 4; j++) {
    int c = tid * 4 + j;
    float o = (x[j] - mean) * inv * g[c] + b[c];
    ((float*)&vo)[j] = o;
    o16[off + c] = (_Float16)o;
  }
  *(float4*)(o32 + off + tid * 4) = vo;
}

// ---------------------------------------------------------------------------

template<int BM, int BN, int EPI, bool RELU, int SPLITK>
static void gemm(hipStream_t st, const _Float16* A, const _Float16* B,
                 const float* b0, const float* b1, const float* b2,
                 void* C0, void* C1, int M, int N, int K,
                 int lda, int ldb, int ldc,
                 int Z, long sAz, long sBz, int cdiv, long sC1, long sC2,
                 int vseg, int bstr)
{
  dim3 g(M / BM, N / BN, Z);
  gemm_k<BM, BN, EPI, RELU, SPLITK><<<g, dim3(256), 0, st>>>(
      A, B, b0, b1, b2, C0, C1, K, lda, ldb, ldc, sAz, sBz, cdiv, sC1, sC2, vseg, bstr);
}

extern "C" void kernel_launch(void* const* d_in, const int* in_sizes, int n_in,
                              void* d_out, int out_size, void* d_ws, size_t ws_size,
                              hipStream_t stream) {
  (void)n_in; (void)out_size; (void)ws_size;
  const float *emb, *cls, *sWq, *sbq, *sWk, *sbk, *sWv, *sbv, *sWo, *sbo;
  const float *cWq, *cbq, *cWk, *cbk, *cWv, *cbv, *cWo, *cbo;
  const float *fW1, *fb1, *fW2, *fb2, *g1, *g2, *g3, *b1, *b2, *b3;
  const int *xt, *yt;
  if (in_sizes[0] == NB * NXTOK) {
    xt = (const int*)d_in[0]; yt = (const int*)d_in[1];
    emb = (const float*)d_in[2]; cls = (const float*)d_in[3];
    sWq = (const float*)d_in[4]; sbq = (const float*)d_in[5];
    sWk = (const float*)d_in[6]; sbk = (const float*)d_in[7];
    sWv = (const float*)d_in[8]; sbv = (const float*)d_in[9];
    sWo = (const float*)d_in[10]; sbo = (const float*)d_in[11];
    cWq = (const float*)d_in[12]; cbq = (const float*)d_in[13];
    cWk = (const float*)d_in[14]; cbk = (const float*)d_in[15];
    cWv = (const float*)d_in[16]; cbv = (const float*)d_in[17];
    cWo = (const float*)d_in[18]; cbo = (const float*)d_in[19];
    g1 = (const float*)d_in[20]; b1 = (const float*)d_in[21];
    g2 = (const float*)d_in[22]; b2 = (const float*)d_in[23];
    g3 = (const float*)d_in[24]; b3 = (const float*)d_in[25];
    fW1 = (const float*)d_in[26]; fb1 = (const float*)d_in[27];
    fW2 = (const float*)d_in[28]; fb2 = (const float*)d_in[29];
  } else {
    emb = (const float*)d_in[0]; cls = (const float*)d_in[1];
    sWq = (const float*)d_in[2]; sbq = (const float*)d_in[3];
    sWk = (const float*)d_in[4]; sbk = (const float*)d_in[5];
    sWv = (const float*)d_in[6]; sbv = (const float*)d_in[7];
    sWo = (const float*)d_in[8]; sbo = (const float*)d_in[9];
    cWq = (const float*)d_in[10]; cbq = (const float*)d_in[11];
    cWk = (const float*)d_in[12]; cbk = (const float*)d_in[13];
    cWv = (const float*)d_in[14]; cbv = (const float*)d_in[15];
    cWo = (const float*)d_in[16]; cbo = (const float*)d_in[17];
    fW1 = (const float*)d_in[18]; fb1 = (const float*)d_in[19];
    fW2 = (const float*)d_in[20]; fb2 = (const float*)d_in[21];
    g1 = (const float*)d_in[22]; g2 = (const float*)d_in[23]; g3 = (const float*)d_in[24];
    b1 = (const float*)d_in[25]; b2 = (const float*)d_in[26]; b3 = (const float*)d_in[27];
    xt = (const int*)d_in[28]; yt = (const int*)d_in[29];
  }

  // ---- ws layout ----
  const size_t MM = (size_t)1 << 20;
  _Float16* W16 = (_Float16*)d_ws;       // weights: 64 MM f16 (4 layers x 16 MM)
  _Float16* qhk_all = W16 + 64 * MM;     // [l]{q 2MM, k 2MM} = 16 MM
  _Float16* vT_all  = W16 + 80 * MM;     // [l] 2MM = 8 MM
  _Float16* ob_all  = W16 + 88 * MM;     // [l] 2MM = 8 MM
  _Float16* y16     = W16 + 96 * MM;     // 2 MM
  _Float16* yl16_all= W16 + 98 * MM;     // [l] 2MM = 8 MM
  _Float16* cqh_all = W16 + 106 * MM;    // [l] 2MM = 8 MM
  _Float16* kh_c    = W16 + 114 * MM;    // 2 MM
  _Float16* vT_c    = W16 + 116 * MM;    // 2 MM
  _Float16* ob_c    = W16 + 118 * MM;    // 2 MM
  _Float16* x16     = W16 + 120 * MM;    // 2 MM
  _Float16* ffn     = W16 + 122 * MM;    // 8 MM
  float* y32      = (float*)(W16 + 130 * MM);  // 2 MM f32
  _Float16* tmp16 = (_Float16*)(y32 + 2 * MM); // 4 x 2MM f16 partials
  float* yl32_all = y32 + 10 * MM;             // 4 x 2MM f32
  float* x32      = y32 + 18 * MM;             // 2 MM f32
  const long SP16 = 2048L * 1024;              // 2MM f16 partial/layer stride

  // ---- upfront: merged weight conversion + embed (1 dispatch) ----
  W8 w8;
  w8.p[0] = sWq; w8.p[1] = sWk; w8.p[2] = sWv; w8.p[3] = cWq;
  w8.p[4] = cWk; w8.p[5] = cWv; w8.p[6] = sWo; w8.p[7] = cWo;
  prep_k<<<dim3(8192), 256, 0, stream>>>(w8, fW1, fW2, W16, xt, yt, emb, cls,
                                         y32, y16, x16);

  // ---- hoisted: entire self-attn branch + cross-q for ALL layers ----
  gemm<128, 128, 2, false, 1>(stream, y16, W16, sbq, sbk, sbv,
      qhk_all, vT_all, 2048, 3072, 1024, 1024, 1024, 0,
      4, 0, 16 * MM, 1, 4 * MM, 2 * MM, 2, 1024);
  flash_k<true><<<dim3(8, 32, 4), 256, 0, stream>>>(
      qhk_all, qhk_all + 2 * MM, vT_all, ob_all, 4 * MM, 4 * MM, 2 * MM, 2 * MM);
  gemm<128, 128, 1, false, 1>(stream, ob_all, W16 + 6 * MM, sbo, nullptr, nullptr,
      tmp16, nullptr, 2048, 1024, 1024, 1024, 1024, 1024,
      4, 2 * MM, 16 * MM, 1, SP16, 0, 0, 1024);
  lnres_k<1><<<dim3(2048, 4), 256, 0, stream>>>(y32, tmp16, nullptr, nullptr, nullptr,
      g1, b1, yl32_all, yl16_all, 0, SP16, 2 * MM, 1024);
  gemm<128, 128, 2, false, 1>(stream, yl16_all, W16 + 3 * MM, cbq, nullptr, nullptr,
      cqh_all, nullptr, 2048, 1024, 1024, 1024, 1024, 0,
      4, 2 * MM, 16 * MM, 1, 2 * MM, 0, 3, 1024);

  // ---- sequential decoder chain ----
  for (int l = 0; l < NLAYER; l++) {
    _Float16* wl   = W16 + (size_t)l * 16 * MM;
    _Float16* wckv = wl + 4 * MM;
    _Float16* wco  = wl + 7 * MM;
    _Float16* wf1  = wl + 8 * MM;
    _Float16* wf2  = wl + 12 * MM;

    gemm<128, 128, 2, false, 1>(stream, x16, wckv, cbk + l * ESZ, cbv + l * ESZ,
        nullptr, kh_c, vT_c, 2048, 2048, 1024, 1024, 1024, 0,
        1, 0, 0, 1, 0, 0, 1, 0);
    flash_k<false><<<dim3(8, 32, 1), 256, 0, stream>>>(
        cqh_all + (size_t)l * 2 * MM, kh_c, vT_c, ob_c, 0, 0, 0, 0);
    gemm<128, 128, 1, false, 4>(stream, ob_c, wco, cbo + l * ESZ, nullptr, nullptr,
        tmp16, nullptr, 2048, 1024, 1024, 1024, 1024, 1024,
        4, 0, 0, 1, SP16, 0, 0, 0);
    lnres_k<4><<<dim3(2048, 1), 256, 0, stream>>>(yl32_all + (size_t)l * 2 * MM,
        tmp16, tmp16 + SP16, tmp16 + 2 * SP16, tmp16 + 3 * SP16,
        g2 + l * ESZ, b2 + l * ESZ, x32, x16, 0, 0, 0, 0);

    gemm<128, 128, 1, true, 1>(stream, x16, wf1, fb1 + l * FFD, nullptr, nullptr,
        ffn, nullptr, 2048, 4096, 1024, 1024, 1024, 4096,
        1, 0, 0, 1, 0, 0, 0, 0);
    gemm<128, 128, 1, false, 4>(stream, ffn, wf2, fb2 + l * ESZ, nullptr, nullptr,
        tmp16, nullptr, 2048, 1024, 4096, 4096, 4096, 1024,
        4, 0, 0, 1, SP16, 0, 0, 0);
    lnres_k<4><<<dim3(2048, 1), 256, 0, stream>>>(x32, tmp16, tmp16 + SP16,
        tmp16 + 2 * SP16, tmp16 + 3 * SP16, g3 + l * ESZ, b3 + l * ESZ,
        (l == NLAYER - 1) ? (float*)d_out : x32, x16, 0, 0, 0, 0);
  }
}

// Round 16
// 798.824 us; speedup vs baseline: 1.1562x; 1.0021x over previous
//
#include <hip/hip_runtime.h>
#include <cstdint>

#define ESZ 1024
#define NH 16
#define HD 64
#define NLAYER 4
#define FFD 4096
#define NB 2
#define NXTOK 1023
#define SEQ 1024
#define LNEPS 1e-5f

typedef __attribute__((ext_vector_type(8))) _Float16 f16x8;
typedef __attribute__((ext_vector_type(4))) _Float16 f16x4;
typedef __attribute__((ext_vector_type(4))) float f32x4;

__device__ __forceinline__ void gld16(const void* g, void* l) {
  __builtin_amdgcn_global_load_lds(
      (const __attribute__((address_space(1))) unsigned int*)g,
      (__attribute__((address_space(3))) unsigned int*)l, 16, 0, 0);
}

// Bijective XCD-aware block swizzle (each XCD gets a contiguous work chunk).
__device__ __forceinline__ uint3 xcd_swz() {
  unsigned gx = gridDim.x, gy = gridDim.y;
  unsigned nwg = gx * gy * gridDim.z;
  unsigned lin = (blockIdx.z * gy + blockIdx.y) * gx + blockIdx.x;
  unsigned q = nwg >> 3, r = nwg & 7;
  unsigned xcd = lin & 7, idx = lin >> 3;
  unsigned wid = (xcd < r ? xcd * (q + 1) : r * (q + 1) + (xcd - r) * q) + idx;
  uint3 o;
  o.x = wid % gx;
  unsigned t = wid / gx;
  o.y = t % gy;
  o.z = t / gy;
  return o;
}

// ---------------------------------------------------------------------------
// Shared GEMM epilogue (non-V blocks). EPI: 0 f32, 1 f16, 2 QKV head scatter.
// ---------------------------------------------------------------------------
template<int MI, int NJ, int EPI, bool RELU, int SPLITK>
__device__ __forceinline__ void gemm_epi(
    f32x4 (&acc)[MI][NJ], int m0, int n0, int wr, int wc, int lr, int hi,
    int z, size_t coff, int ldc,
    const float* bias0, const float* bias1, const float* bias2, int bstr,
    void* C0, void* C1, long sC1, long sC2, int vseg)
{
  const int rb = hi * 4;
#pragma unroll
  for (int j = 0; j < NJ; j++) {
    const int n = n0 + wc + j * 16 + lr;
    float bv = 0.f;
    if (EPI == 2) {
      int seg = n >> 10;
      const float* bp = (seg == 0) ? bias0 : ((seg == 1) ? bias1 : bias2);
      bv = bp[bstr * z + (n & 1023)];
    } else if (bias0) bv = bias0[bstr * z + n];
    if (SPLITK > 1 && z > 0) bv = 0.f;
#pragma unroll
    for (int i = 0; i < MI; i++) {
#pragma unroll
      for (int r = 0; r < 4; r++) {
        int row = m0 + wr + i * 16 + rb + r;
        float out = acc[i][j][r] + bv;
        if (RELU) out = fmaxf(out, 0.f);
        if (EPI == 0) {
          ((float*)C0)[coff + (size_t)row * ldc + n] = out;
        } else if (EPI == 1) {
          ((_Float16*)C0)[coff + (size_t)row * ldc + n] = (_Float16)out;
        } else {
          int seg = n >> 10, n1 = n & 1023, h = n1 >> 6, d = n1 & 63;
          int b = row >> 10, s = row & 1023;
          if (seg == vseg)
            ((_Float16*)C1)[(size_t)z * sC2 + (((size_t)b * NH + h) * HD + d) * SEQ + s] = (_Float16)out;
          else
            ((_Float16*)C0)[(size_t)z * sC1 + (size_t)seg * ((size_t)NB * NH * SEQ * HD)
                            + (((size_t)b * NH + h) * SEQ + s) * HD + d] = (_Float16)out;
        }
      }
    }
  }
}

// ---------------------------------------------------------------------------
// 4-wave NT MFMA GEMM, BM=BN=128, BK=64, DOUBLE-buffered 64 KB LDS (T3
// 2-phase pipeline supplies overlap at ~1-2 blocks/CU grids). 8-row XOR
// swizzle -> 0 bank conflicts. EPI==2 V-blocks: LDS-transpose epilogue.
// ---------------------------------------------------------------------------
template<int BM, int BN, int EPI, bool RELU, int SPLITK>
__global__ __launch_bounds__(256)
void gemm_k(const _Float16* __restrict__ A, const _Float16* __restrict__ Bm,
            const float* __restrict__ bias0, const float* __restrict__ bias1,
            const float* __restrict__ bias2,
            void* __restrict__ C0, void* __restrict__ C1,
            int K, int lda, int ldb, int ldc,
            long sAz, long sBz, int cdiv, long sC1, long sC2, int vseg, int bstr)
{
  constexpr int MI = BM / 32, NJ = BN / 32;
  constexpr int DBUF = 2 * (BM + BN) * 64;
  constexpr int TBUF = (EPI == 2) ? 128 * 136 : 0;
  constexpr int LDSN = (TBUF > DBUF) ? TBUF : DBUF;
  __shared__ _Float16 lds[LDSN];

  const uint3 bi = xcd_swz();
  const int m0 = bi.x * BM;
  const int n0 = bi.y * BN;
  const int z = bi.z;
  const _Float16* Ab;
  const _Float16* Bb;
  size_t coff;
  if (SPLITK > 1) {
    int koff = z * (K / SPLITK);
    Ab = A + koff;
    Bb = Bm + koff;
    coff = (size_t)z * sC1;
  } else {
    Ab = A + (size_t)z * sAz;
    Bb = Bm + (size_t)z * sBz;
    coff = (size_t)(z / cdiv) * sC1 + (size_t)(z % cdiv) * sC2;
  }
  const int tid = threadIdx.x;
  const int lane = tid & 63;
  const int w = tid >> 6;
  const int lr = lane & 15;
  const int hi = lane >> 4;
  const int wr = (w >> 1) * (BM / 2);
  const int wc = (w & 1) * (BN / 2);

  const f32x4 vz = {0.f, 0.f, 0.f, 0.f};
  f32x4 acc[MI][NJ];
#pragma unroll
  for (int i = 0; i < MI; i++)
#pragma unroll
    for (int j = 0; j < NJ; j++) acc[i][j] = vz;

  const int nk = (K / SPLITK) >> 6;

  auto stage = [&](int buf, int kt) {
    const int k0 = kt << 6;
    _Float16* Ah = lds + buf * (BM * 64);
    _Float16* Bh = lds + 2 * (BM * 64) + buf * (BN * 64);
#pragma unroll
    for (int c = 0; c < MI; c++) {
      int r = w * (BM / 4) + c * 8 + (lane >> 3);
      int cg = ((lane & 7) ^ (r & 7)) << 3;
      gld16(Ab + (size_t)(m0 + r) * lda + k0 + cg, Ah + (w * (BM / 4) + c * 8) * 64);
    }
#pragma unroll
    for (int c = 0; c < NJ; c++) {
      int r = w * (BN / 4) + c * 8 + (lane >> 3);
      int cg = ((lane & 7) ^ (r & 7)) << 3;
      gld16(Bb + (size_t)(n0 + r) * ldb + k0 + cg, Bh + (w * (BN / 4) + c * 8) * 64);
    }
  };

  stage(0, 0);
  int cur = 0;
  for (int kt = 0; kt < nk; ++kt) {
    __syncthreads();
    if (kt + 1 < nk) stage(cur ^ 1, kt + 1);
    const char* Ah = (const char*)(lds + cur * (BM * 64));
    const char* Bh = (const char*)(lds + 2 * (BM * 64) + cur * (BN * 64));
#pragma unroll
    for (int kk = 0; kk < 2; kk++) {
      f16x8 af[MI], bf[NJ];
#pragma unroll
      for (int i = 0; i < MI; i++) {
        int row = wr + i * 16 + lr;
        int off = ((kk << 6) | (hi << 4)) ^ ((row & 7) << 4);
        af[i] = *(const f16x8*)(Ah + row * 128 + off);
      }
#pragma unroll
      for (int j = 0; j < NJ; j++) {
        int row = wc + j * 16 + lr;
        int off = ((kk << 6) | (hi << 4)) ^ ((row & 7) << 4);
        bf[j] = *(const f16x8*)(Bh + row * 128 + off);
      }
#pragma unroll
      for (int i = 0; i < MI; i++)
#pragma unroll
        for (int j = 0; j < NJ; j++)
          acc[i][j] = __builtin_amdgcn_mfma_f32_16x16x32_f16(af[i], bf[j], acc[i][j], 0, 0, 0);
    }
    cur ^= 1;
  }

  if (EPI == 2 && (n0 >> 10) == vseg) {
    __syncthreads();
    _Float16* T = lds;   // [128][136]
    const float* bp = (vseg == 0) ? bias0 : ((vseg == 1) ? bias1 : bias2);
#pragma unroll
    for (int j = 0; j < NJ; j++) {
      int nloc = wc + j * 16 + lr;
      float bv = bp[bstr * z + ((n0 + nloc) & 1023)];
#pragma unroll
      for (int i = 0; i < MI; i++) {
        f16x4 tv;
#pragma unroll
        for (int r = 0; r < 4; r++) tv[r] = (_Float16)(acc[i][j][r] + bv);
        *(f16x4*)(T + nloc * 136 + wr + i * 16 + hi * 4) = tv;
      }
    }
    __syncthreads();
    int rowT = tid >> 1;
    int c0 = (tid & 1) << 6;
    int nn = (n0 & 1023) + rowT;
    int h = nn >> 6, d = nn & 63;
    int bb = m0 >> 10;
    int s0 = (m0 & 1023) + c0;
    _Float16* dst = (_Float16*)C1 + (size_t)z * sC2
                  + (((size_t)bb * NH + h) * HD + d) * SEQ + s0;
    const _Float16* src = T + rowT * 136 + c0;
#pragma unroll
    for (int t2 = 0; t2 < 8; t2++)
      *(f16x8*)(dst + t2 * 8) = *(const f16x8*)(src + t2 * 8);
    return;
  }

  gemm_epi<MI, NJ, EPI, RELU, SPLITK>(acc, m0, n0, wr, wc, lr, hi, z, coff, ldc,
                                      bias0, bias1, bias2, bstr, C0, C1, sC1, sC2, vseg);
}

// ---------------------------------------------------------------------------
// Flash attention: one block = 128 q rows of one (b,h); 4 waves x 32 q rows.
// blockIdx.z = layer. Swapped QK^T; S^T C-layout IS the B-fragment of
// mfma_16x16x16_f16 so PV needs no P relayout. setprio around MFMA clusters.
// ---------------------------------------------------------------------------
template<bool CAUSAL>
__global__ __launch_bounds__(256)
void flash_k(const _Float16* __restrict__ qh, const _Float16* __restrict__ kh,
             const _Float16* __restrict__ vTp, _Float16* __restrict__ ob,
             long qs, long ks, long vs, long os)
{
  __shared__ _Float16 Kl[2][64 * 64];
  __shared__ _Float16 Vl[2][64 * 64];
  const uint3 bi = xcd_swz();
  const int qb = bi.x;
  const int bh = bi.y;
  const int layer = bi.z;
  const int b = bh >> 4, h = bh & 15;
  const int q0 = qb * 128;
  const int tid = threadIdx.x;
  const int w = tid >> 6, lane = tid & 63;
  const int lr = lane & 15, hi = lane >> 4;
  const int qw = q0 + w * 32;

  const _Float16* Qp = qh + (size_t)layer * qs + (size_t)bh * SEQ * HD;
  const _Float16* Kp = kh + (size_t)layer * ks + (size_t)bh * SEQ * HD;
  const _Float16* Vp = vTp + (size_t)layer * vs + (size_t)bh * HD * SEQ;
  ob += (size_t)layer * os;

  f16x8 qf[2][2];
#pragma unroll
  for (int jq = 0; jq < 2; jq++)
#pragma unroll
    for (int ds = 0; ds < 2; ds++)
      qf[jq][ds] = *(const f16x8*)(Qp + (size_t)(qw + jq * 16 + lr) * HD + ds * 32 + hi * 8);

  float m[2] = {-1e30f, -1e30f}, l[2] = {0.f, 0.f};
  const f32x4 vz = {0.f, 0.f, 0.f, 0.f};
  f32x4 o[4][2];
#pragma unroll
  for (int dt = 0; dt < 4; dt++)
#pragma unroll
    for (int jq = 0; jq < 2; jq++) o[dt][jq] = vz;

  const int nst = CAUSAL ? ((q0 >> 6) + 2) : (SEQ / 64);

  auto stage = [&](int buf, int kt) {
    const int k0 = kt << 6;
#pragma unroll
    for (int c = 0; c < 2; c++) {
      int r = w * 16 + c * 8 + (lane >> 3);
      int cg = ((lane & 7) ^ (r & 7)) << 3;
      gld16(Kp + (size_t)(k0 + r) * HD + cg, &Kl[buf][(w * 16 + c * 8) * 64]);
      gld16(Vp + (size_t)r * SEQ + k0 + cg, &Vl[buf][(w * 16 + c * 8) * 64]);
    }
  };

  stage(0, 0);
  int cur = 0;
  for (int kt = 0; kt < nst; ++kt) {
    __syncthreads();
    if (kt + 1 < nst) stage(cur ^ 1, kt + 1);
    const int k0 = kt << 6;
    if (!CAUSAL || k0 <= qw + 31) {
      f32x4 s[4][2];
#pragma unroll
      for (int ik = 0; ik < 4; ik++)
#pragma unroll
        for (int jq = 0; jq < 2; jq++) s[ik][jq] = vz;
#pragma unroll
      for (int ds = 0; ds < 2; ds++) {
        f16x8 kf[4];
#pragma unroll
        for (int ik = 0; ik < 4; ik++) {
          int row = ik * 16 + lr;
          int off = (ds * 64 + hi * 16) ^ ((row & 7) << 4);
          kf[ik] = *(const f16x8*)((const char*)&Kl[cur][0] + row * 128 + off);
        }
        __builtin_amdgcn_s_setprio(1);
#pragma unroll
        for (int ik = 0; ik < 4; ik++)
#pragma unroll
          for (int jq = 0; jq < 2; jq++)
            s[ik][jq] = __builtin_amdgcn_mfma_f32_16x16x32_f16(kf[ik], qf[jq][ds], s[ik][jq], 0, 0, 0);
        __builtin_amdgcn_s_setprio(0);
      }
      float mx[2] = {-1e30f, -1e30f};
#pragma unroll
      for (int ik = 0; ik < 4; ik++)
#pragma unroll
        for (int jq = 0; jq < 2; jq++)
#pragma unroll
          for (int r = 0; r < 4; r++) {
            float v = s[ik][jq][r] * 0.03125f;
            if (CAUSAL) {
              int kk = k0 + ik * 16 + hi * 4 + r;
              int qq = qw + jq * 16 + lr;
              if (kk > qq) v = -1e30f;
            }
            s[ik][jq][r] = v;
            mx[jq] = fmaxf(mx[jq], v);
          }
      float sc[2], cs[2] = {0.f, 0.f};
      f16x4 pb[4][2];
#pragma unroll
      for (int jq = 0; jq < 2; jq++) {
        mx[jq] = fmaxf(mx[jq], __shfl_xor(mx[jq], 16, 64));
        mx[jq] = fmaxf(mx[jq], __shfl_xor(mx[jq], 32, 64));
        float mn = fmaxf(m[jq], mx[jq]);
        sc[jq] = __expf(m[jq] - mn);
        m[jq] = mn;
      }
#pragma unroll
      for (int ik = 0; ik < 4; ik++)
#pragma unroll
        for (int jq = 0; jq < 2; jq++)
#pragma unroll
          for (int r = 0; r < 4; r++) {
            float p = __expf(s[ik][jq][r] - m[jq]);
            cs[jq] += p;
            pb[ik][jq][r] = (_Float16)p;
          }
#pragma unroll
      for (int jq = 0; jq < 2; jq++) {
        float t = cs[jq];
        t += __shfl_xor(t, 16, 64);
        t += __shfl_xor(t, 32, 64);
        l[jq] = l[jq] * sc[jq] + t;
      }
#pragma unroll
      for (int dt = 0; dt < 4; dt++)
#pragma unroll
        for (int jq = 0; jq < 2; jq++)
#pragma unroll
          for (int r = 0; r < 4; r++) o[dt][jq][r] *= sc[jq];
#pragma unroll
      for (int ks2 = 0; ks2 < 4; ks2++) {
        f16x4 va[4];
#pragma unroll
        for (int dt = 0; dt < 4; dt++) {
          int row = dt * 16 + lr;
          int off = (ks2 * 32 + hi * 8) ^ ((row & 7) << 4);
          va[dt] = *(const f16x4*)((const char*)&Vl[cur][0] + row * 128 + off);
        }
        __builtin_amdgcn_s_setprio(1);
#pragma unroll
        for (int dt = 0; dt < 4; dt++)
#pragma unroll
          for (int jq = 0; jq < 2; jq++)
            o[dt][jq] = __builtin_amdgcn_mfma_f32_16x16x16f16(va[dt], pb[ks2][jq], o[dt][jq], 0, 0, 0);
        __builtin_amdgcn_s_setprio(0);
      }
    }
    cur ^= 1;
  }

  float inv[2] = {1.f / l[0], 1.f / l[1]};
#pragma unroll
  for (int jq = 0; jq < 2; jq++) {
    int q = qw + jq * 16 + lr;
    size_t rowoff = (size_t)(b * SEQ + q) * ESZ + h * 64;
#pragma unroll
    for (int dt = 0; dt < 4; dt++) {
      f16x4 ov;
#pragma unroll
      for (int r = 0; r < 4; r++) ov[r] = (_Float16)(o[dt][jq][r] * inv[jq]);
      *(f16x4*)(ob + rowoff + dt * 16 + hi * 4) = ov;
    }
  }
}

// ---------------------------------------------------------------------------
// Merged prep: weight convert+transpose + embedding/PE, one dispatch.
// wtr3: stage the 128x128 f32 tile into LDS via global_load_lds (16
// back-to-back gld16/wave, 2 rows per call: lanes 0-31 row r, 32-63 row
// r+1 -- per-lane global addresses, linear LDS dest) -> deep async pipe
// with zero VGPR cost (fixes the 2-3-deep compiler serialization that
// pinned VALU preps at ~2.8 TB/s). Then barrier, LDS readback, in-register
// transpose, coalesced f16x8 stores.
// ---------------------------------------------------------------------------
__device__ __forceinline__ void wtr3(const float* __restrict__ src,
                                     _Float16* __restrict__ dst,
                                     int K, int Ns, int k0, int n0, int tid,
                                     float* T)
{
  const int w = tid >> 6, lane = tid & 63;
  {
    const int rh = lane >> 5;          // which of the 2 rows per gld16
    const int cl = lane & 31;          // 32 lanes x 16B = 512B = 128 f32
#pragma unroll
    for (int c = 0; c < 16; c++) {
      int r = w * 32 + c * 2;
      gld16(src + (size_t)(k0 + r + rh) * Ns + n0 + cl * 4, T + r * 128);
    }
  }
  __syncthreads();
  const int nb = lane & 15;
  const int kb = lane >> 4;
  const int kk = w * 32 + kb * 8;
  const int nn = nb * 8;
  f32x4 v[8], u[8];
#pragma unroll
  for (int i = 0; i < 8; i++) {
    const f32x4* p = (const f32x4*)(T + (kk + i) * 128 + nn);
    v[i] = p[0];
    u[i] = p[1];
  }
#pragma unroll
  for (int j = 0; j < 8; j++) {
    f16x8 o;
#pragma unroll
    for (int i = 0; i < 8; i++) {
      float f = (j < 4) ? v[i][j] : u[i][j - 4];
      o[i] = (_Float16)f;
    }
    *(f16x8*)(dst + (size_t)(n0 + nn + j) * K + k0 + kk) = o;
  }
  __syncthreads();
}

struct W8 { const float* p[8]; };

__global__ __launch_bounds__(256)
void prep_k(W8 w8, const float* __restrict__ fW1, const float* __restrict__ fW2,
            _Float16* __restrict__ W16,
            const int* __restrict__ xt, const int* __restrict__ yt,
            const float* __restrict__ emb, const float* __restrict__ cls,
            float* __restrict__ y32, _Float16* __restrict__ y16,
            _Float16* __restrict__ x16)
{
  __shared__ float T[128 * 128];
  const size_t MM = (size_t)1 << 20;
  int idx = blockIdx.x;
  int tid = threadIdx.x;
  if (idx < 2048) {
    int z = idx >> 6, rem = idx & 63;
    int widx = z >> 2, layer = z & 3;
    const float* src = w8.p[widx] + (size_t)layer * (ESZ * ESZ);
    _Float16* dst = W16 + (size_t)layer * 16 * MM + (size_t)widx * MM;
    wtr3(src, dst, 1024, 1024, (rem & 7) * 128, (rem >> 3) * 128, tid, T);
    return;
  }
  if (idx < 3072) {
    int i = idx - 2048;
    int z = i >> 8, rem = i & 255;
    wtr3(fW1 + (size_t)z * ESZ * FFD, W16 + (size_t)z * 16 * MM + 8 * MM,
         1024, 4096, (rem & 7) * 128, (rem >> 3) * 128, tid, T);
    return;
  }
  if (idx < 4096) {
    int i = idx - 3072;
    int z = i >> 8, rem = i & 255;
    wtr3(fW2 + (size_t)z * ESZ * FFD, W16 + (size_t)z * 16 * MM + 12 * MM,
         4096, 1024, (rem & 31) * 128, (rem >> 5) * 128, tid, T);
    return;
  }
  int row = idx - 4096;
  bool isx = row < NB * SEQ;
  int rr = isx ? row : row - NB * SEQ;
  int b = rr >> 10, tpos = rr & (SEQ - 1);
  int col0 = tid * 4;
  float v[4];
  if (isx && tpos == SEQ - 1) {
#pragma unroll
    for (int j = 0; j < 4; j++) v[j] = cls[col0 + j];
  } else {
    int tok = isx ? xt[b * NXTOK + tpos] : yt[b * SEQ + tpos];
    const float* erow = emb + (size_t)tok * ESZ;
#pragma unroll
    for (int j = 0; j < 4; j++) {
      int e = col0 + j;
      float div = expf((float)(e & ~1) * (-9.210340371976184f / 1024.f));
      float ang = (float)b * div;
      float pe = (e & 1) ? cosf(ang) : sinf(ang);
      v[j] = erow[e] * 32.f + pe;
    }
  }
  size_t off = (size_t)rr * ESZ + col0;
  if (isx) {
#pragma unroll
    for (int j = 0; j < 4; j++) x16[off + j] = (_Float16)v[j];
  } else {
#pragma unroll
    for (int j = 0; j < 4; j++) { y32[off + j] = v[j]; y16[off + j] = (_Float16)v[j]; }
  }
}

// ---------------------------------------------------------------------------
// out = LN(a + sum of NP f16 partials)*g + b; writes f32 + f16.
// blockIdx.y = layer (batched): strides aStr/rStr/oStr/gStr.
// ---------------------------------------------------------------------------
template<int NP>
__global__ __launch_bounds__(256)
void lnres_k(const float* __restrict__ a, const _Float16* __restrict__ r0,
             const _Float16* __restrict__ r1, const _Float16* __restrict__ r2,
             const _Float16* __restrict__ r3,
             const float* __restrict__ g, const float* __restrict__ b,
             float* __restrict__ o32, _Float16* __restrict__ o16,
             long aStr, long rStr, long oStr, int gStr)
{
  int row = blockIdx.x;
  int lz = blockIdx.y;
  a += (size_t)lz * aStr;
  r0 += (size_t)lz * rStr;
  o32 += (size_t)lz * oStr;
  o16 += (size_t)lz * oStr;
  g += (size_t)lz * gStr;
  b += (size_t)lz * gStr;
  size_t off = (size_t)row * ESZ;
  int tid = threadIdx.x;
  float4 va = *(const float4*)(a + off + tid * 4);
  float x[4] = {va.x, va.y, va.z, va.w};
  {
    f16x4 v = *(const f16x4*)(r0 + off + tid * 4);
#pragma unroll
    for (int j = 0; j < 4; j++) x[j] += (float)v[j];
  }
  if (NP >= 2) {
    f16x4 v = *(const f16x4*)(r1 + off + tid * 4);
#pragma unroll
    for (int j = 0; j < 4; j++) x[j] += (float)v[j];
  }
  if (NP >= 4) {
    f16x4 v = *(const f16x4*)(r2 + off + tid * 4);
    f16x4 u = *(const f16x4*)(r3 + off + tid * 4);
#pragma unroll
    for (int j = 0; j < 4; j++) x[j] += (float)v[j] + (float)u[j];
  }
  float s = x[0] + x[1] + x[2] + x[3];
  float s2 = x[0] * x[0] + x[1] * x[1] + x[2] * x[2] + x[3] * x[3];
  for (int o = 32; o > 0; o >>= 1) {
    s += __shfl_xor(s, o, 64);
    s2 += __shfl_xor(s2, o, 64);
  }
  __shared__ float rs[4], rs2[4];
  if ((tid & 63) == 0) { rs[tid >> 6] = s; rs2[tid >> 6] = s2; }
  __syncthreads();
  s = rs[0] + rs[1] + rs[2] + rs[3];
  s2 = rs2[0] + rs2[1] + rs2[2] + rs2[3];
  float mean = s * (1.f / ESZ);
  float var = s2 * (1.f / ESZ) - mean * mean;
  float inv = 1.f / sqrtf(var + LNEPS);
  float4 vo;
#pragma unroll
  for (int j = 0; j < 4; j++) {
    int c = tid * 4 + j;
    float o = (x[j] - mean) * inv * g[c] + b[c];
    ((float*)&vo)[j] = o;
    o16[off + c] = (_Float16)o;
  }
  *(float4*)(o32 + off + tid * 4) = vo;
}

// ---------------------------------------------------------------------------

template<int BM, int BN, int EPI, bool RELU, int SPLITK>
static void gemm(hipStream_t st, const _Float16* A, const _Float16* B,
                 const float* b0, const float* b1, const float* b2,
                 void* C0, void* C1, int M, int N, int K,
                 int lda, int ldb, int ldc,
                 int Z, long sAz, long sBz, int cdiv, long sC1, long sC2,
                 int vseg, int bstr)
{
  dim3 g(M / BM, N / BN, Z);
  gemm_k<BM, BN, EPI, RELU, SPLITK><<<g, dim3(256), 0, st>>>(
      A, B, b0, b1, b2, C0, C1, K, lda, ldb, ldc, sAz, sBz, cdiv, sC1, sC2, vseg, bstr);
}

extern "C" void kernel_launch(void* const* d_in, const int* in_sizes, int n_in,
                              void* d_out, int out_size, void* d_ws, size_t ws_size,
                              hipStream_t stream) {
  (void)n_in; (void)out_size; (void)ws_size;
  const float *emb, *cls, *sWq, *sbq, *sWk, *sbk, *sWv, *sbv, *sWo, *sbo;
  const float *cWq, *cbq, *cWk, *cbk, *cWv, *cbv, *cWo, *cbo;
  const float *fW1, *fb1, *fW2, *fb2, *g1, *g2, *g3, *b1, *b2, *b3;
  const int *xt, *yt;
  if (in_sizes[0] == NB * NXTOK) {
    xt = (const int*)d_in[0]; yt = (const int*)d_in[1];
    emb = (const float*)d_in[2]; cls = (const float*)d_in[3];
    sWq = (const float*)d_in[4]; sbq = (const float*)d_in[5];
    sWk = (const float*)d_in[6]; sbk = (const float*)d_in[7];
    sWv = (const float*)d_in[8]; sbv = (const float*)d_in[9];
    sWo = (const float*)d_in[10]; sbo = (const float*)d_in[11];
    cWq = (const float*)d_in[12]; cbq = (const float*)d_in[13];
    cWk = (const float*)d_in[14]; cbk = (const float*)d_in[15];
    cWv = (const float*)d_in[16]; cbv = (const float*)d_in[17];
    cWo = (const float*)d_in[18]; cbo = (const float*)d_in[19];
    g1 = (const float*)d_in[20]; b1 = (const float*)d_in[21];
    g2 = (const float*)d_in[22]; b2 = (const float*)d_in[23];
    g3 = (const float*)d_in[24]; b3 = (const float*)d_in[25];
    fW1 = (const float*)d_in[26]; fb1 = (const float*)d_in[27];
    fW2 = (const float*)d_in[28]; fb2 = (const float*)d_in[29];
  } else {
    emb = (const float*)d_in[0]; cls = (const float*)d_in[1];
    sWq = (const float*)d_in[2]; sbq = (const float*)d_in[3];
    sWk = (const float*)d_in[4]; sbk = (const float*)d_in[5];
    sWv = (const float*)d_in[6]; sbv = (const float*)d_in[7];
    sWo = (const float*)d_in[8]; sbo = (const float*)d_in[9];
    cWq = (const float*)d_in[10]; cbq = (const float*)d_in[11];
    cWk = (const float*)d_in[12]; cbk = (const float*)d_in[13];
    cWv = (const float*)d_in[14]; cbv = (const float*)d_in[15];
    cWo = (const float*)d_in[16]; cbo = (const float*)d_in[17];
    fW1 = (const float*)d_in[18]; fb1 = (const float*)d_in[19];
    fW2 = (const float*)d_in[20]; fb2 = (const float*)d_in[21];
    g1 = (const float*)d_in[22]; g2 = (const float*)d_in[23]; g3 = (const float*)d_in[24];
    b1 = (const float*)d_in[25]; b2 = (const float*)d_in[26]; b3 = (const float*)d_in[27];
    xt = (const int*)d_in[28]; yt = (const int*)d_in[29];
  }

  // ---- ws layout ----
  const size_t MM = (size_t)1 << 20;
  _Float16* W16 = (_Float16*)d_ws;       // weights: 64 MM f16 (4 layers x 16 MM)
  _Float16* qhk_all = W16 + 64 * MM;     // [l]{q 2MM, k 2MM} = 16 MM
  _Float16* vT_all  = W16 + 80 * MM;     // [l] 2MM = 8 MM
  _Float16* ob_all  = W16 + 88 * MM;     // [l] 2MM = 8 MM
  _Float16* y16     = W16 + 96 * MM;     // 2 MM
  _Float16* yl16_all= W16 + 98 * MM;     // [l] 2MM = 8 MM
  _Float16* cqh_all = W16 + 106 * MM;    // [l] 2MM = 8 MM
  _Float16* kh_c    = W16 + 114 * MM;    // 2 MM
  _Float16* vT_c    = W16 + 116 * MM;    // 2 MM
  _Float16* ob_c    = W16 + 118 * MM;    // 2 MM
  _Float16* x16     = W16 + 120 * MM;    // 2 MM
  _Float16* ffn     = W16 + 122 * MM;    // 8 MM
  float* y32      = (float*)(W16 + 130 * MM);  // 2 MM f32
  _Float16* tmp16 = (_Float16*)(y32 + 2 * MM); // 4 x 2MM f16 partials
  float* yl32_all = y32 + 10 * MM;             // 4 x 2MM f32
  float* x32      = y32 + 18 * MM;             // 2 MM f32
  const long SP16 = 2048L * 1024;              // 2MM f16 partial/layer stride

  // ---- upfront: merged weight conversion + embed (1 dispatch) ----
  W8 w8;
  w8.p[0] = sWq; w8.p[1] = sWk; w8.p[2] = sWv; w8.p[3] = cWq;
  w8.p[4] = cWk; w8.p[5] = cWv; w8.p[6] = sWo; w8.p[7] = cWo;
  prep_k<<<dim3(8192), 256, 0, stream>>>(w8, fW1, fW2, W16, xt, yt, emb, cls,
                                         y32, y16, x16);

  // ---- hoisted: entire self-attn branch + cross-q for ALL layers ----
  gemm<128, 128, 2, false, 1>(stream, y16, W16, sbq, sbk, sbv,
      qhk_all, vT_all, 2048, 3072, 1024, 1024, 1024, 0,
      4, 0, 16 * MM, 1, 4 * MM, 2 * MM, 2, 1024);
  flash_k<true><<<dim3(8, 32, 4), 256, 0, stream>>>(
      qhk_all, qhk_all + 2 * MM, vT_all, ob_all, 4 * MM, 4 * MM, 2 * MM, 2 * MM);
  gemm<128, 128, 1, false, 1>(stream, ob_all, W16 + 6 * MM, sbo, nullptr, nullptr,
      tmp16, nullptr, 2048, 1024, 1024, 1024, 1024, 1024,
      4, 2 * MM, 16 * MM, 1, SP16, 0, 0, 1024);
  lnres_k<1><<<dim3(2048, 4), 256, 0, stream>>>(y32, tmp16, nullptr, nullptr, nullptr,
      g1, b1, yl32_all, yl16_all, 0, SP16, 2 * MM, 1024);
  gemm<128, 128, 2, false, 1>(stream, yl16_all, W16 + 3 * MM, cbq, nullptr, nullptr,
      cqh_all, nullptr, 2048, 1024, 1024, 1024, 1024, 0,
      4, 2 * MM, 16 * MM, 1, 2 * MM, 0, 3, 1024);

  // ---- sequential decoder chain ----
  for (int l = 0; l < NLAYER; l++) {
    _Float16* wl   = W16 + (size_t)l * 16 * MM;
    _Float16* wckv = wl + 4 * MM;
    _Float16* wco  = wl + 7 * MM;
    _Float16* wf1  = wl + 8 * MM;
    _Float16* wf2  = wl + 12 * MM;

    gemm<128, 128, 2, false, 1>(stream, x16, wckv, cbk + l * ESZ, cbv + l * ESZ,
        nullptr, kh_c, vT_c, 2048, 2048, 1024, 1024, 1024, 0,
        1, 0, 0, 1, 0, 0, 1, 0);
    flash_k<false><<<dim3(8, 32, 1), 256, 0, stream>>>(
        cqh_all + (size_t)l * 2 * MM, kh_c, vT_c, ob_c, 0, 0, 0, 0);
    gemm<128, 128, 1, false, 4>(stream, ob_c, wco, cbo + l * ESZ, nullptr, nullptr,
        tmp16, nullptr, 2048, 1024, 1024, 1024, 1024, 1024,
        4, 0, 0, 1, SP16, 0, 0, 0);
    lnres_k<4><<<dim3(2048, 1), 256, 0, stream>>>(yl32_all + (size_t)l * 2 * MM,
        tmp16, tmp16 + SP16, tmp16 + 2 * SP16, tmp16 + 3 * SP16,
        g2 + l * ESZ, b2 + l * ESZ, x32, x16, 0, 0, 0, 0);

    gemm<128, 128, 1, true, 1>(stream, x16, wf1, fb1 + l * FFD, nullptr, nullptr,
        ffn, nullptr, 2048, 4096, 1024, 1024, 1024, 4096,
        1, 0, 0, 1, 0, 0, 0, 0);
    gemm<128, 128, 1, false, 4>(stream, ffn, wf2, fb2 + l * ESZ, nullptr, nullptr,
        tmp16, nullptr, 2048, 1024, 4096, 4096, 4096, 1024,
        4, 0, 0, 1, SP16, 0, 0, 0);
    lnres_k<4><<<dim3(2048, 1), 256, 0, stream>>>(x32, tmp16, tmp16 + SP16,
        tmp16 + 2 * SP16, tmp16 + 3 * SP16, g3 + l * ESZ, b3 + l * ESZ,
        (l == NLAYER - 1) ? (float*)d_out : x32, x16, 0, 0, 0, 0);
  }
}

// Round 17
// 788.827 us; speedup vs baseline: 1.1708x; 1.0127x over previous
//
#include <hip/hip_runtime.h>
#include <cstdint>

#define ESZ 1024
#define NH 16
#define HD 64
#define NLAYER 4
#define FFD 4096
#define NB 2
#define NXTOK 1023
#define SEQ 1024
#define LNEPS 1e-5f

typedef __attribute__((ext_vector_type(8))) _Float16 f16x8;
typedef __attribute__((ext_vector_type(4))) _Float16 f16x4;
typedef __attribute__((ext_vector_type(4))) float f32x4;

__device__ __forceinline__ void gld16(const void* g, void* l) {
  __builtin_amdgcn_global_load_lds(
      (const __attribute__((address_space(1))) unsigned int*)g,
      (__attribute__((address_space(3))) unsigned int*)l, 16, 0, 0);
}

// Bijective XCD-aware block swizzle (each XCD gets a contiguous work chunk).
__device__ __forceinline__ uint3 xcd_swz() {
  unsigned gx = gridDim.x, gy = gridDim.y;
  unsigned nwg = gx * gy * gridDim.z;
  unsigned lin = (blockIdx.z * gy + blockIdx.y) * gx + blockIdx.x;
  unsigned q = nwg >> 3, r = nwg & 7;
  unsigned xcd = lin & 7, idx = lin >> 3;
  unsigned wid = (xcd < r ? xcd * (q + 1) : r * (q + 1) + (xcd - r) * q) + idx;
  uint3 o;
  o.x = wid % gx;
  unsigned t = wid / gx;
  o.y = t % gy;
  o.z = t / gy;
  return o;
}

// ---------------------------------------------------------------------------
// Shared GEMM epilogue (non-V blocks). EPI: 0 f32, 1 f16, 2 QKV head scatter.
// ---------------------------------------------------------------------------
template<int MI, int NJ, int EPI, bool RELU, int SPLITK>
__device__ __forceinline__ void gemm_epi(
    f32x4 (&acc)[MI][NJ], int m0, int n0, int wr, int wc, int lr, int hi,
    int z, size_t coff, int ldc,
    const float* bias0, const float* bias1, const float* bias2, int bstr,
    void* C0, void* C1, long sC1, long sC2, int vseg)
{
  const int rb = hi * 4;
#pragma unroll
  for (int j = 0; j < NJ; j++) {
    const int n = n0 + wc + j * 16 + lr;
    float bv = 0.f;
    if (EPI == 2) {
      int seg = n >> 10;
      const float* bp = (seg == 0) ? bias0 : ((seg == 1) ? bias1 : bias2);
      bv = bp[bstr * z + (n & 1023)];
    } else if (bias0) bv = bias0[bstr * z + n];
    if (SPLITK > 1 && z > 0) bv = 0.f;
#pragma unroll
    for (int i = 0; i < MI; i++) {
#pragma unroll
      for (int r = 0; r < 4; r++) {
        int row = m0 + wr + i * 16 + rb + r;
        float out = acc[i][j][r] + bv;
        if (RELU) out = fmaxf(out, 0.f);
        if (EPI == 0) {
          ((float*)C0)[coff + (size_t)row * ldc + n] = out;
        } else if (EPI == 1) {
          ((_Float16*)C0)[coff + (size_t)row * ldc + n] = (_Float16)out;
        } else {
          int seg = n >> 10, n1 = n & 1023, h = n1 >> 6, d = n1 & 63;
          int b = row >> 10, s = row & 1023;
          if (seg == vseg)
            ((_Float16*)C1)[(size_t)z * sC2 + (((size_t)b * NH + h) * HD + d) * SEQ + s] = (_Float16)out;
          else
            ((_Float16*)C0)[(size_t)z * sC1 + (size_t)seg * ((size_t)NB * NH * SEQ * HD)
                            + (((size_t)b * NH + h) * SEQ + s) * HD + d] = (_Float16)out;
        }
      }
    }
  }
}

// ---------------------------------------------------------------------------
// 4-wave NT MFMA GEMM, BM=BN=128, BK=64, DOUBLE-buffered 64 KB LDS (T3
// 2-phase pipeline supplies overlap at ~1-2 blocks/CU grids). 8-row XOR
// swizzle -> 0 bank conflicts. EPI==2 V-blocks: LDS-transpose epilogue.
// ---------------------------------------------------------------------------
template<int BM, int BN, int EPI, bool RELU, int SPLITK>
__global__ __launch_bounds__(256)
void gemm_k(const _Float16* __restrict__ A, const _Float16* __restrict__ Bm,
            const float* __restrict__ bias0, const float* __restrict__ bias1,
            const float* __restrict__ bias2,
            void* __restrict__ C0, void* __restrict__ C1,
            int K, int lda, int ldb, int ldc,
            long sAz, long sBz, int cdiv, long sC1, long sC2, int vseg, int bstr)
{
  constexpr int MI = BM / 32, NJ = BN / 32;
  constexpr int DBUF = 2 * (BM + BN) * 64;
  constexpr int TBUF = (EPI == 2) ? 128 * 136 : 0;
  constexpr int LDSN = (TBUF > DBUF) ? TBUF : DBUF;
  __shared__ _Float16 lds[LDSN];

  const uint3 bi = xcd_swz();
  const int m0 = bi.x * BM;
  const int n0 = bi.y * BN;
  const int z = bi.z;
  const _Float16* Ab;
  const _Float16* Bb;
  size_t coff;
  if (SPLITK > 1) {
    int koff = z * (K / SPLITK);
    Ab = A + koff;
    Bb = Bm + koff;
    coff = (size_t)z * sC1;
  } else {
    Ab = A + (size_t)z * sAz;
    Bb = Bm + (size_t)z * sBz;
    coff = (size_t)(z / cdiv) * sC1 + (size_t)(z % cdiv) * sC2;
  }
  const int tid = threadIdx.x;
  const int lane = tid & 63;
  const int w = tid >> 6;
  const int lr = lane & 15;
  const int hi = lane >> 4;
  const int wr = (w >> 1) * (BM / 2);
  const int wc = (w & 1) * (BN / 2);

  const f32x4 vz = {0.f, 0.f, 0.f, 0.f};
  f32x4 acc[MI][NJ];
#pragma unroll
  for (int i = 0; i < MI; i++)
#pragma unroll
    for (int j = 0; j < NJ; j++) acc[i][j] = vz;

  const int nk = (K / SPLITK) >> 6;

  auto stage = [&](int buf, int kt) {
    const int k0 = kt << 6;
    _Float16* Ah = lds + buf * (BM * 64);
    _Float16* Bh = lds + 2 * (BM * 64) + buf * (BN * 64);
#pragma unroll
    for (int c = 0; c < MI; c++) {
      int r = w * (BM / 4) + c * 8 + (lane >> 3);
      int cg = ((lane & 7) ^ (r & 7)) << 3;
      gld16(Ab + (size_t)(m0 + r) * lda + k0 + cg, Ah + (w * (BM / 4) + c * 8) * 64);
    }
#pragma unroll
    for (int c = 0; c < NJ; c++) {
      int r = w * (BN / 4) + c * 8 + (lane >> 3);
      int cg = ((lane & 7) ^ (r & 7)) << 3;
      gld16(Bb + (size_t)(n0 + r) * ldb + k0 + cg, Bh + (w * (BN / 4) + c * 8) * 64);
    }
  };

  stage(0, 0);
  int cur = 0;
  for (int kt = 0; kt < nk; ++kt) {
    __syncthreads();
    if (kt + 1 < nk) stage(cur ^ 1, kt + 1);
    const char* Ah = (const char*)(lds + cur * (BM * 64));
    const char* Bh = (const char*)(lds + 2 * (BM * 64) + cur * (BN * 64));
#pragma unroll
    for (int kk = 0; kk < 2; kk++) {
      f16x8 af[MI], bf[NJ];
#pragma unroll
      for (int i = 0; i < MI; i++) {
        int row = wr + i * 16 + lr;
        int off = ((kk << 6) | (hi << 4)) ^ ((row & 7) << 4);
        af[i] = *(const f16x8*)(Ah + row * 128 + off);
      }
#pragma unroll
      for (int j = 0; j < NJ; j++) {
        int row = wc + j * 16 + lr;
        int off = ((kk << 6) | (hi << 4)) ^ ((row & 7) << 4);
        bf[j] = *(const f16x8*)(Bh + row * 128 + off);
      }
#pragma unroll
      for (int i = 0; i < MI; i++)
#pragma unroll
        for (int j = 0; j < NJ; j++)
          acc[i][j] = __builtin_amdgcn_mfma_f32_16x16x32_f16(af[i], bf[j], acc[i][j], 0, 0, 0);
    }
    cur ^= 1;
  }

  if (EPI == 2 && (n0 >> 10) == vseg) {
    __syncthreads();
    _Float16* T = lds;   // [128][136]
    const float* bp = (vseg == 0) ? bias0 : ((vseg == 1) ? bias1 : bias2);
#pragma unroll
    for (int j = 0; j < NJ; j++) {
      int nloc = wc + j * 16 + lr;
      float bv = bp[bstr * z + ((n0 + nloc) & 1023)];
#pragma unroll
      for (int i = 0; i < MI; i++) {
        f16x4 tv;
#pragma unroll
        for (int r = 0; r < 4; r++) tv[r] = (_Float16)(acc[i][j][r] + bv);
        *(f16x4*)(T + nloc * 136 + wr + i * 16 + hi * 4) = tv;
      }
    }
    __syncthreads();
    int rowT = tid >> 1;
    int c0 = (tid & 1) << 6;
    int nn = (n0 & 1023) + rowT;
    int h = nn >> 6, d = nn & 63;
    int bb = m0 >> 10;
    int s0 = (m0 & 1023) + c0;
    _Float16* dst = (_Float16*)C1 + (size_t)z * sC2
                  + (((size_t)bb * NH + h) * HD + d) * SEQ + s0;
    const _Float16* src = T + rowT * 136 + c0;
#pragma unroll
    for (int t2 = 0; t2 < 8; t2++)
      *(f16x8*)(dst + t2 * 8) = *(const f16x8*)(src + t2 * 8);
    return;
  }

  gemm_epi<MI, NJ, EPI, RELU, SPLITK>(acc, m0, n0, wr, wc, lr, hi, z, coff, ldc,
                                      bias0, bias1, bias2, bstr, C0, C1, sC1, sC2, vseg);
}

// ---------------------------------------------------------------------------
// Flash attention: one block = 128 q rows of one (b,h); 4 waves x 32 q rows.
// blockIdx.z = layer. Swapped QK^T; S^T C-layout IS the B-fragment of
// mfma_16x16x16_f16 so PV needs no P relayout. setprio around MFMA clusters.
// ---------------------------------------------------------------------------
template<bool CAUSAL>
__global__ __launch_bounds__(256)
void flash_k(const _Float16* __restrict__ qh, const _Float16* __restrict__ kh,
             const _Float16* __restrict__ vTp, _Float16* __restrict__ ob,
             long qs, long ks, long vs, long os)
{
  __shared__ _Float16 Kl[2][64 * 64];
  __shared__ _Float16 Vl[2][64 * 64];
  const uint3 bi = xcd_swz();
  const int qb = bi.x;
  const int bh = bi.y;
  const int layer = bi.z;
  const int b = bh >> 4, h = bh & 15;
  const int q0 = qb * 128;
  const int tid = threadIdx.x;
  const int w = tid >> 6, lane = tid & 63;
  const int lr = lane & 15, hi = lane >> 4;
  const int qw = q0 + w * 32;

  const _Float16* Qp = qh + (size_t)layer * qs + (size_t)bh * SEQ * HD;
  const _Float16* Kp = kh + (size_t)layer * ks + (size_t)bh * SEQ * HD;
  const _Float16* Vp = vTp + (size_t)layer * vs + (size_t)bh * HD * SEQ;
  ob += (size_t)layer * os;

  f16x8 qf[2][2];
#pragma unroll
  for (int jq = 0; jq < 2; jq++)
#pragma unroll
    for (int ds = 0; ds < 2; ds++)
      qf[jq][ds] = *(const f16x8*)(Qp + (size_t)(qw + jq * 16 + lr) * HD + ds * 32 + hi * 8);

  float m[2] = {-1e30f, -1e30f}, l[2] = {0.f, 0.f};
  const f32x4 vz = {0.f, 0.f, 0.f, 0.f};
  f32x4 o[4][2];
#pragma unroll
  for (int dt = 0; dt < 4; dt++)
#pragma unroll
    for (int jq = 0; jq < 2; jq++) o[dt][jq] = vz;

  const int nst = CAUSAL ? ((q0 >> 6) + 2) : (SEQ / 64);

  auto stage = [&](int buf, int kt) {
    const int k0 = kt << 6;
#pragma unroll
    for (int c = 0; c < 2; c++) {
      int r = w * 16 + c * 8 + (lane >> 3);
      int cg = ((lane & 7) ^ (r & 7)) << 3;
      gld16(Kp + (size_t)(k0 + r) * HD + cg, &Kl[buf][(w * 16 + c * 8) * 64]);
      gld16(Vp + (size_t)r * SEQ + k0 + cg, &Vl[buf][(w * 16 + c * 8) * 64]);
    }
  };

  stage(0, 0);
  int cur = 0;
  for (int kt = 0; kt < nst; ++kt) {
    __syncthreads();
    if (kt + 1 < nst) stage(cur ^ 1, kt + 1);
    const int k0 = kt << 6;
    if (!CAUSAL || k0 <= qw + 31) {
      f32x4 s[4][2];
#pragma unroll
      for (int ik = 0; ik < 4; ik++)
#pragma unroll
        for (int jq = 0; jq < 2; jq++) s[ik][jq] = vz;
#pragma unroll
      for (int ds = 0; ds < 2; ds++) {
        f16x8 kf[4];
#pragma unroll
        for (int ik = 0; ik < 4; ik++) {
          int row = ik * 16 + lr;
          int off = (ds * 64 + hi * 16) ^ ((row & 7) << 4);
          kf[ik] = *(const f16x8*)((const char*)&Kl[cur][0] + row * 128 + off);
        }
        __builtin_amdgcn_s_setprio(1);
#pragma unroll
        for (int ik = 0; ik < 4; ik++)
#pragma unroll
          for (int jq = 0; jq < 2; jq++)
            s[ik][jq] = __builtin_amdgcn_mfma_f32_16x16x32_f16(kf[ik], qf[jq][ds], s[ik][jq], 0, 0, 0);
        __builtin_amdgcn_s_setprio(0);
      }
      float mx[2] = {-1e30f, -1e30f};
#pragma unroll
      for (int ik = 0; ik < 4; ik++)
#pragma unroll
        for (int jq = 0; jq < 2; jq++)
#pragma unroll
          for (int r = 0; r < 4; r++) {
            float v = s[ik][jq][r] * 0.03125f;
            if (CAUSAL) {
              int kk = k0 + ik * 16 + hi * 4 + r;
              int qq = qw + jq * 16 + lr;
              if (kk > qq) v = -1e30f;
            }
            s[ik][jq][r] = v;
            mx[jq] = fmaxf(mx[jq], v);
          }
      float sc[2], cs[2] = {0.f, 0.f};
      f16x4 pb[4][2];
#pragma unroll
      for (int jq = 0; jq < 2; jq++) {
        mx[jq] = fmaxf(mx[jq], __shfl_xor(mx[jq], 16, 64));
        mx[jq] = fmaxf(mx[jq], __shfl_xor(mx[jq], 32, 64));
        float mn = fmaxf(m[jq], mx[jq]);
        sc[jq] = __expf(m[jq] - mn);
        m[jq] = mn;
      }
#pragma unroll
      for (int ik = 0; ik < 4; ik++)
#pragma unroll
        for (int jq = 0; jq < 2; jq++)
#pragma unroll
          for (int r = 0; r < 4; r++) {
            float p = __expf(s[ik][jq][r] - m[jq]);
            cs[jq] += p;
            pb[ik][jq][r] = (_Float16)p;
          }
#pragma unroll
      for (int jq = 0; jq < 2; jq++) {
        float t = cs[jq];
        t += __shfl_xor(t, 16, 64);
        t += __shfl_xor(t, 32, 64);
        l[jq] = l[jq] * sc[jq] + t;
      }
#pragma unroll
      for (int dt = 0; dt < 4; dt++)
#pragma unroll
        for (int jq = 0; jq < 2; jq++)
#pragma unroll
          for (int r = 0; r < 4; r++) o[dt][jq][r] *= sc[jq];
#pragma unroll
      for (int ks2 = 0; ks2 < 4; ks2++) {
        f16x4 va[4];
#pragma unroll
        for (int dt = 0; dt < 4; dt++) {
          int row = dt * 16 + lr;
          int off = (ks2 * 32 + hi * 8) ^ ((row & 7) << 4);
          va[dt] = *(const f16x4*)((const char*)&Vl[cur][0] + row * 128 + off);
        }
        __builtin_amdgcn_s_setprio(1);
#pragma unroll
        for (int dt = 0; dt < 4; dt++)
#pragma unroll
          for (int jq = 0; jq < 2; jq++)
            o[dt][jq] = __builtin_amdgcn_mfma_f32_16x16x16f16(va[dt], pb[ks2][jq], o[dt][jq], 0, 0, 0);
        __builtin_amdgcn_s_setprio(0);
      }
    }
    cur ^= 1;
  }

  float inv[2] = {1.f / l[0], 1.f / l[1]};
#pragma unroll
  for (int jq = 0; jq < 2; jq++) {
    int q = qw + jq * 16 + lr;
    size_t rowoff = (size_t)(b * SEQ + q) * ESZ + h * 64;
#pragma unroll
    for (int dt = 0; dt < 4; dt++) {
      f16x4 ov;
#pragma unroll
      for (int r = 0; r < 4; r++) ov[r] = (_Float16)(o[dt][jq][r] * inv[jq]);
      *(f16x4*)(ob + rowoff + dt * 16 + hi * 4) = ov;
    }
  }
}

// ---------------------------------------------------------------------------
// Merged prep: weight convert+transpose + embedding/PE, one dispatch.
// LDS-free transpose, 8k x 8n per thread, 16 plain f32x4 loads followed by
// sched_barrier(0): pins ALL loads before the convert/store code so the
// scheduler can't sink them (the 2-3-deep interleave that capped plain-load
// preps at 2.5 TB/s). Plain loads keep L2/L3 in the path (NT bypass cost
// +100 MB HBM in R14).
// ---------------------------------------------------------------------------
__device__ __forceinline__ void wtr2(const float* __restrict__ src,
                                     _Float16* __restrict__ dst,
                                     int K, int Ns, int k0, int n0, int tid)
{
  const int w = tid >> 6, lane = tid & 63;
  const int nb = lane & 15;
  const int kb = lane >> 4;
  const int kbase = k0 + w * 32 + kb * 8;
  const int nbase = n0 + nb * 8;
  f32x4 v[8], u[8];
#pragma unroll
  for (int i = 0; i < 8; i++) {
    const f32x4* p = (const f32x4*)(src + (size_t)(kbase + i) * Ns + nbase);
    v[i] = p[0];
    u[i] = p[1];
  }
  __builtin_amdgcn_sched_barrier(0);   // all 16 loads issued before any store
#pragma unroll
  for (int j = 0; j < 8; j++) {
    f16x8 o;
#pragma unroll
    for (int i = 0; i < 8; i++) {
      float f = (j < 4) ? v[i][j] : u[i][j - 4];
      o[i] = (_Float16)f;
    }
    *(f16x8*)(dst + (size_t)(nbase + j) * K + kbase) = o;
  }
}

struct W8 { const float* p[8]; };

__global__ __launch_bounds__(256)
void prep_k(W8 w8, const float* __restrict__ fW1, const float* __restrict__ fW2,
            _Float16* __restrict__ W16,
            const int* __restrict__ xt, const int* __restrict__ yt,
            const float* __restrict__ emb, const float* __restrict__ cls,
            float* __restrict__ y32, _Float16* __restrict__ y16,
            _Float16* __restrict__ x16)
{
  const size_t MM = (size_t)1 << 20;
  int idx = blockIdx.x;
  int tid = threadIdx.x;
  if (idx < 2048) {
    int z = idx >> 6, rem = idx & 63;
    int widx = z >> 2, layer = z & 3;
    const float* src = w8.p[widx] + (size_t)layer * (ESZ * ESZ);
    _Float16* dst = W16 + (size_t)layer * 16 * MM + (size_t)widx * MM;
    wtr2(src, dst, 1024, 1024, (rem & 7) * 128, (rem >> 3) * 128, tid);
    return;
  }
  if (idx < 3072) {
    int i = idx - 2048;
    int z = i >> 8, rem = i & 255;
    wtr2(fW1 + (size_t)z * ESZ * FFD, W16 + (size_t)z * 16 * MM + 8 * MM,
         1024, 4096, (rem & 7) * 128, (rem >> 3) * 128, tid);
    return;
  }
  if (idx < 4096) {
    int i = idx - 3072;
    int z = i >> 8, rem = i & 255;
    wtr2(fW2 + (size_t)z * ESZ * FFD, W16 + (size_t)z * 16 * MM + 12 * MM,
         4096, 1024, (rem & 31) * 128, (rem >> 5) * 128, tid);
    return;
  }
  int row = idx - 4096;
  bool isx = row < NB * SEQ;
  int rr = isx ? row : row - NB * SEQ;
  int b = rr >> 10, tpos = rr & (SEQ - 1);
  int col0 = tid * 4;
  float v[4];
  if (isx && tpos == SEQ - 1) {
#pragma unroll
    for (int j = 0; j < 4; j++) v[j] = cls[col0 + j];
  } else {
    int tok = isx ? xt[b * NXTOK + tpos] : yt[b * SEQ + tpos];
    const float* erow = emb + (size_t)tok * ESZ;
#pragma unroll
    for (int j = 0; j < 4; j++) {
      int e = col0 + j;
      float div = expf((float)(e & ~1) * (-9.210340371976184f / 1024.f));
      float ang = (float)b * div;
      float pe = (e & 1) ? cosf(ang) : sinf(ang);
      v[j] = erow[e] * 32.f + pe;
    }
  }
  size_t off = (size_t)rr * ESZ + col0;
  if (isx) {
#pragma unroll
    for (int j = 0; j < 4; j++) x16[off + j] = (_Float16)v[j];
  } else {
#pragma unroll
    for (int j = 0; j < 4; j++) { y32[off + j] = v[j]; y16[off + j] = (_Float16)v[j]; }
  }
}

// ---------------------------------------------------------------------------
// out = LN(a + sum of NP f16 partials)*g + b; writes f32 + f16.
// blockIdx.y = layer (batched): strides aStr/rStr/oStr/gStr.
// ---------------------------------------------------------------------------
template<int NP>
__global__ __launch_bounds__(256)
void lnres_k(const float* __restrict__ a, const _Float16* __restrict__ r0,
             const _Float16* __restrict__ r1, const _Float16* __restrict__ r2,
             const _Float16* __restrict__ r3,
             const float* __restrict__ g, const float* __restrict__ b,
             float* __restrict__ o32, _Float16* __restrict__ o16,
             long aStr, long rStr, long oStr, int gStr)
{
  int row = blockIdx.x;
  int lz = blockIdx.y;
  a += (size_t)lz * aStr;
  r0 += (size_t)lz * rStr;
  o32 += (size_t)lz * oStr;
  o16 += (size_t)lz * oStr;
  g += (size_t)lz * gStr;
  b += (size_t)lz * gStr;
  size_t off = (size_t)row * ESZ;
  int tid = threadIdx.x;
  float4 va = *(const float4*)(a + off + tid * 4);
  float x[4] = {va.x, va.y, va.z, va.w};
  {
    f16x4 v = *(const f16x4*)(r0 + off + tid * 4);
#pragma unroll
    for (int j = 0; j < 4; j++) x[j] += (float)v[j];
  }
  if (NP >= 2) {
    f16x4 v = *(const f16x4*)(r1 + off + tid * 4);
#pragma unroll
    for (int j = 0; j < 4; j++) x[j] += (float)v[j];
  }
  if (NP >= 4) {
    f16x4 v = *(const f16x4*)(r2 + off + tid * 4);
    f16x4 u = *(const f16x4*)(r3 + off + tid * 4);
#pragma unroll
    for (int j = 0; j < 4; j++) x[j] += (float)v[j] + (float)u[j];
  }
  float s = x[0] + x[1] + x[2] + x[3];
  float s2 = x[0] * x[0] + x[1] * x[1] + x[2] * x[2] + x[3] * x[3];
  for (int o = 32; o > 0; o >>= 1) {
    s += __shfl_xor(s, o, 64);
    s2 += __shfl_xor(s2, o, 64);
  }
  __shared__ float rs[4], rs2[4];
  if ((tid & 63) == 0) { rs[tid >> 6] = s; rs2[tid >> 6] = s2; }
  __syncthreads();
  s = rs[0] + rs[1] + rs[2] + rs[3];
  s2 = rs2[0] + rs2[1] + rs2[2] + rs2[3];
  float mean = s * (1.f / ESZ);
  float var = s2 * (1.f / ESZ) - mean * mean;
  float inv = 1.f / sqrtf(var + LNEPS);
  float4 vo;
#pragma unroll
  for (int j = 0; j < 4; j++) {
    int c = tid * 4 + j;
    float o = (x[j] - mean) * inv * g[c] + b[c];
    ((float*)&vo)[j] = o;
    o16[off + c] = (_Float16)o;
  }
  *(float4*)(o32 + off + tid * 4) = vo;
}

// ---------------------------------------------------------------------------

template<int BM, int BN, int EPI, bool RELU, int SPLITK>
static void gemm(hipStream_t st, const _Float16* A, const _Float16* B,
                 const float* b0, const float* b1, const float* b2,
                 void* C0, void* C1, int M, int N, int K,
                 int lda, int ldb, int ldc,
                 int Z, long sAz, long sBz, int cdiv, long sC1, long sC2,
                 int vseg, int bstr)
{
  dim3 g(M / BM, N / BN, Z);
  gemm_k<BM, BN, EPI, RELU, SPLITK><<<g, dim3(256), 0, st>>>(
      A, B, b0, b1, b2, C0, C1, K, lda, ldb, ldc, sAz, sBz, cdiv, sC1, sC2, vseg, bstr);
}

extern "C" void kernel_launch(void* const* d_in, const int* in_sizes, int n_in,
                              void* d_out, int out_size, void* d_ws, size_t ws_size,
                              hipStream_t stream) {
  (void)n_in; (void)out_size; (void)ws_size;
  const float *emb, *cls, *sWq, *sbq, *sWk, *sbk, *sWv, *sbv, *sWo, *sbo;
  const float *cWq, *cbq, *cWk, *cbk, *cWv, *cbv, *cWo, *cbo;
  const float *fW1, *fb1, *fW2, *fb2, *g1, *g2, *g3, *b1, *b2, *b3;
  const int *xt, *yt;
  if (in_sizes[0] == NB * NXTOK) {
    xt = (const int*)d_in[0]; yt = (const int*)d_in[1];
    emb = (const float*)d_in[2]; cls = (const float*)d_in[3];
    sWq = (const float*)d_in[4]; sbq = (const float*)d_in[5];
    sWk = (const float*)d_in[6]; sbk = (const float*)d_in[7];
    sWv = (const float*)d_in[8]; sbv = (const float*)d_in[9];
    sWo = (const float*)d_in[10]; sbo = (const float*)d_in[11];
    cWq = (const float*)d_in[12]; cbq = (const float*)d_in[13];
    cWk = (const float*)d_in[14]; cbk = (const float*)d_in[15];
    cWv = (const float*)d_in[16]; cbv = (const float*)d_in[17];
    cWo = (const float*)d_in[18]; cbo = (const float*)d_in[19];
    g1 = (const float*)d_in[20]; b1 = (const float*)d_in[21];
    g2 = (const float*)d_in[22]; b2 = (const float*)d_in[23];
    g3 = (const float*)d_in[24]; b3 = (const float*)d_in[25];
    fW1 = (const float*)d_in[26]; fb1 = (const float*)d_in[27];
    fW2 = (const float*)d_in[28]; fb2 = (const float*)d_in[29];
  } else {
    emb = (const float*)d_in[0]; cls = (const float*)d_in[1];
    sWq = (const float*)d_in[2]; sbq = (const float*)d_in[3];
    sWk = (const float*)d_in[4]; sbk = (const float*)d_in[5];
    sWv = (const float*)d_in[6]; sbv = (const float*)d_in[7];
    sWo = (const float*)d_in[8]; sbo = (const float*)d_in[9];
    cWq = (const float*)d_in[10]; cbq = (const float*)d_in[11];
    cWk = (const float*)d_in[12]; cbk = (const float*)d_in[13];
    cWv = (const float*)d_in[14]; cbv = (const float*)d_in[15];
    cWo = (const float*)d_in[16]; cbo = (const float*)d_in[17];
    fW1 = (const float*)d_in[18]; fb1 = (const float*)d_in[19];
    fW2 = (const float*)d_in[20]; fb2 = (const float*)d_in[21];
    g1 = (const float*)d_in[22]; g2 = (const float*)d_in[23]; g3 = (const float*)d_in[24];
    b1 = (const float*)d_in[25]; b2 = (const float*)d_in[26]; b3 = (const float*)d_in[27];
    xt = (const int*)d_in[28]; yt = (const int*)d_in[29];
  }

  // ---- ws layout ----
  const size_t MM = (size_t)1 << 20;
  _Float16* W16 = (_Float16*)d_ws;       // weights: 64 MM f16 (4 layers x 16 MM)
  _Float16* qhk_all = W16 + 64 * MM;     // [l]{q 2MM, k 2MM} = 16 MM
  _Float16* vT_all  = W16 + 80 * MM;     // [l] 2MM = 8 MM
  _Float16* ob_all  = W16 + 88 * MM;     // [l] 2MM = 8 MM
  _Float16* y16     = W16 + 96 * MM;     // 2 MM
  _Float16* yl16_all= W16 + 98 * MM;     // [l] 2MM = 8 MM
  _Float16* cqh_all = W16 + 106 * MM;    // [l] 2MM = 8 MM
  _Float16* kh_c    = W16 + 114 * MM;    // 2 MM
  _Float16* vT_c    = W16 + 116 * MM;    // 2 MM
  _Float16* ob_c    = W16 + 118 * MM;    // 2 MM
  _Float16* x16     = W16 + 120 * MM;    // 2 MM
  _Float16* ffn     = W16 + 122 * MM;    // 8 MM
  float* y32      = (float*)(W16 + 130 * MM);  // 2 MM f32
  _Float16* tmp16 = (_Float16*)(y32 + 2 * MM); // 4 x 2MM f16 partials
  float* yl32_all = y32 + 10 * MM;             // 4 x 2MM f32
  float* x32      = y32 + 18 * MM;             // 2 MM f32
  const long SP16 = 2048L * 1024;              // 2MM f16 partial/layer stride

  // ---- upfront: merged weight conversion + embed (1 dispatch) ----
  W8 w8;
  w8.p[0] = sWq; w8.p[1] = sWk; w8.p[2] = sWv; w8.p[3] = cWq;
  w8.p[4] = cWk; w8.p[5] = cWv; w8.p[6] = sWo; w8.p[7] = cWo;
  prep_k<<<dim3(8192), 256, 0, stream>>>(w8, fW1, fW2, W16, xt, yt, emb, cls,
                                         y32, y16, x16);

  // ---- hoisted: entire self-attn branch + cross-q for ALL layers ----
  gemm<128, 128, 2, false, 1>(stream, y16, W16, sbq, sbk, sbv,
      qhk_all, vT_all, 2048, 3072, 1024, 1024, 1024, 0,
      4, 0, 16 * MM, 1, 4 * MM, 2 * MM, 2, 1024);
  flash_k<true><<<dim3(8, 32, 4), 256, 0, stream>>>(
      qhk_all, qhk_all + 2 * MM, vT_all, ob_all, 4 * MM, 4 * MM, 2 * MM, 2 * MM);
  gemm<128, 128, 1, false, 1>(stream, ob_all, W16 + 6 * MM, sbo, nullptr, nullptr,
      tmp16, nullptr, 2048, 1024, 1024, 1024, 1024, 1024,
      4, 2 * MM, 16 * MM, 1, SP16, 0, 0, 1024);
  lnres_k<1><<<dim3(2048, 4), 256, 0, stream>>>(y32, tmp16, nullptr, nullptr, nullptr,
      g1, b1, yl32_all, yl16_all, 0, SP16, 2 * MM, 1024);
  gemm<128, 128, 2, false, 1>(stream, yl16_all, W16 + 3 * MM, cbq, nullptr, nullptr,
      cqh_all, nullptr, 2048, 1024, 1024, 1024, 1024, 0,
      4, 2 * MM, 16 * MM, 1, 2 * MM, 0, 3, 1024);

  // ---- sequential decoder chain ----
  for (int l = 0; l < NLAYER; l++) {
    _Float16* wl   = W16 + (size_t)l * 16 * MM;
    _Float16* wckv = wl + 4 * MM;
    _Float16* wco  = wl + 7 * MM;
    _Float16* wf1  = wl + 8 * MM;
    _Float16* wf2  = wl + 12 * MM;

    gemm<128, 128, 2, false, 1>(stream, x16, wckv, cbk + l * ESZ, cbv + l * ESZ,
        nullptr, kh_c, vT_c, 2048, 2048, 1024, 1024, 1024, 0,
        1, 0, 0, 1, 0, 0, 1, 0);
    flash_k<false><<<dim3(8, 32, 1), 256, 0, stream>>>(
        cqh_all + (size_t)l * 2 * MM, kh_c, vT_c, ob_c, 0, 0, 0, 0);
    gemm<128, 128, 1, false, 2>(stream, ob_c, wco, cbo + l * ESZ, nullptr, nullptr,
        tmp16, nullptr, 2048, 1024, 1024, 1024, 1024, 1024,
        2, 0, 0, 1, SP16, 0, 0, 0);
    lnres_k<2><<<dim3(2048, 1), 256, 0, stream>>>(yl32_all + (size_t)l * 2 * MM,
        tmp16, tmp16 + SP16, nullptr, nullptr,
        g2 + l * ESZ, b2 + l * ESZ, x32, x16, 0, 0, 0, 0);

    gemm<128, 128, 1, true, 1>(stream, x16, wf1, fb1 + l * FFD, nullptr, nullptr,
        ffn, nullptr, 2048, 4096, 1024, 1024, 1024, 4096,
        1, 0, 0, 1, 0, 0, 0, 0);
    gemm<128, 128, 1, false, 4>(stream, ffn, wf2, fb2 + l * ESZ, nullptr, nullptr,
        tmp16, nullptr, 2048, 1024, 4096, 4096, 4096, 1024,
        4, 0, 0, 1, SP16, 0, 0, 0);
    lnres_k<4><<<dim3(2048, 1), 256, 0, stream>>>(x32, tmp16, tmp16 + SP16,
        tmp16 + 2 * SP16, tmp16 + 3 * SP16, g3 + l * ESZ, b3 + l * ESZ,
        (l == NLAYER - 1) ? (float*)d_out : x32, x16, 0, 0, 0, 0);
  }
}